// Round 1
// baseline (3089.588 us; speedup 1.0000x reference)
//
#include <hip/hip_runtime.h>
#include <hip/hip_bf16.h>
#include <math.h>

// Dims: E=512 M=1024 T=1024 H=512 V=10000 ; B=16 S=80 L=200 ; K=10

typedef __bf16 bf16x8 __attribute__((ext_vector_type(8)));
typedef float f32x4 __attribute__((ext_vector_type(4)));
typedef unsigned short u16x8 __attribute__((ext_vector_type(8)));

__device__ inline unsigned short f2b(float f){
  union { float f; unsigned u; } v; v.f = f;
  unsigned u = v.u;
  u += 0x7fff + ((u >> 16) & 1);       // round-to-nearest-even
  return (unsigned short)(u >> 16);
}
__device__ inline float sigm(float x){ return 1.f/(1.f + __expf(-x)); }
__device__ inline float wred_max(float v){ for (int o=32;o;o>>=1) v = fmaxf(v, __shfl_xor(v,o)); return v; }
__device__ inline float wred_sum(float v){ for (int o=32;o;o>>=1) v += __shfl_xor(v,o); return v; }

__device__ inline float bred_max(float v, float* sm){
  v = wred_max(v);
  int w = threadIdx.x >> 6;
  if ((threadIdx.x & 63) == 0) sm[w] = v;
  __syncthreads();
  v = fmaxf(fmaxf(sm[0], sm[1]), fmaxf(sm[2], sm[3]));
  __syncthreads();
  return v;
}
__device__ inline float bred_sum(float v, float* sm){
  v = wred_sum(v);
  int w = threadIdx.x >> 6;
  if ((threadIdx.x & 63) == 0) sm[w] = v;
  __syncthreads();
  v = sm[0] + sm[1] + sm[2] + sm[3];
  __syncthreads();
  return v;
}

// ---------------------------------------------------------------------------
// Generic C = A @ W^T + b1 + b2.  A:(R,K) f32, W:(N,K) f32 (converted to bf16
// in registers during staging), C:(R,N) f32.  64x64 tile, BK=32, 256 thr.
// grid = (ceil(N/64), R/64). R must be a multiple of 64; K a multiple of 32.
// ---------------------------------------------------------------------------
__global__ __launch_bounds__(256) void gemm_bf16_kernel(
    const float* __restrict__ A, const float* __restrict__ W,
    const float* __restrict__ bias1, const float* __restrict__ bias2,
    float* __restrict__ C, int N, int K)
{
  __shared__ unsigned short lA[64*40];   // +8 pad elems per row
  __shared__ unsigned short lB[64*40];
  int tid = threadIdx.x;
  int n0 = blockIdx.x << 6;
  int r0 = blockIdx.y << 6;
  int wv = tid >> 6, lane = tid & 63;
  int srow = tid >> 2, scol = (tid & 3) << 3;
  f32x4 acc[4];
#pragma unroll
  for (int c=0;c<4;c++) acc[c] = (f32x4){0.f,0.f,0.f,0.f};
  const float* ag = A + (size_t)(r0 + srow)*K + scol;
  int brow = n0 + srow;
  const float* bg = W + (size_t)brow*K + scol;
  bool bok = brow < N;
  int lm = lane & 15, lq = lane >> 4;
  int aoff = (wv*16 + lm)*40 + lq*8;

  for (int k0 = 0; k0 < K; k0 += 32){
    float4 a0 = *(const float4*)(ag + k0);
    float4 a1 = *(const float4*)(ag + k0 + 4);
    float4 b0 = make_float4(0,0,0,0), b1 = make_float4(0,0,0,0);
    if (bok){ b0 = *(const float4*)(bg + k0); b1 = *(const float4*)(bg + k0 + 4); }
    u16x8 av, bv;
    av[0]=f2b(a0.x); av[1]=f2b(a0.y); av[2]=f2b(a0.z); av[3]=f2b(a0.w);
    av[4]=f2b(a1.x); av[5]=f2b(a1.y); av[6]=f2b(a1.z); av[7]=f2b(a1.w);
    bv[0]=f2b(b0.x); bv[1]=f2b(b0.y); bv[2]=f2b(b0.z); bv[3]=f2b(b0.w);
    bv[4]=f2b(b1.x); bv[5]=f2b(b1.y); bv[6]=f2b(b1.z); bv[7]=f2b(b1.w);
    *(u16x8*)&lA[srow*40 + scol] = av;
    *(u16x8*)&lB[srow*40 + scol] = bv;
    __syncthreads();
    bf16x8 af = *(const bf16x8*)&lA[aoff];
#pragma unroll
    for (int c=0;c<4;c++){
      bf16x8 bf = *(const bf16x8*)&lB[(c*16 + lm)*40 + lq*8];
      acc[c] = __builtin_amdgcn_mfma_f32_16x16x32_bf16(af, bf, acc[c], 0, 0, 0);
    }
    __syncthreads();
  }
  // C/D layout: col = lane&15, row = (lane>>4)*4 + reg  [m89/m91 verified]
  int rbase = r0 + wv*16 + lq*4;
#pragma unroll
  for (int c=0;c<4;c++){
    int n = n0 + c*16 + lm;
    if (n < N){
      float bv2 = (bias1 ? bias1[n] : 0.f) + (bias2 ? bias2[n] : 0.f);
#pragma unroll
      for (int r=0;r<4;r++)
        C[(size_t)(rbase + r)*N + n] = acc[c][r] + bv2;
    }
  }
}

// ---------------------------------------------------------------------------
// y = x * softmax(x) over rows of 1024; write into out[row*ostride + ooff + i]
// ---------------------------------------------------------------------------
__global__ __launch_bounds__(256) void rowsmx_kernel(const float* __restrict__ X,
    float* __restrict__ out, int ostride, int ooff)
{
  __shared__ float sm[4];
  int row = blockIdx.x, tid = threadIdx.x;
  const float* xr = X + (size_t)row * 1024;
  float x[4];
#pragma unroll
  for (int j=0;j<4;j++) x[j] = xr[j*256 + tid];
  float m = fmaxf(fmaxf(x[0],x[1]), fmaxf(x[2],x[3]));
  m = bred_max(m, sm);
  float s = 0.f;
#pragma unroll
  for (int j=0;j<4;j++) s += __expf(x[j]-m);
  s = bred_sum(s, sm);
  float inv = 1.f / s;
  float* o = out + (size_t)row*ostride + ooff;
#pragma unroll
  for (int j=0;j<4;j++) o[j*256 + tid] = x[j] * (__expf(x[j]-m) * inv);
}

__global__ void embcopy_kernel(const float* __restrict__ emb, float* __restrict__ mm_inp){
  int idx = blockIdx.x*256 + threadIdx.x;
  if (idx >= 1280*512) return;
  int row = idx >> 9, c = idx & 511;
  mm_inp[(size_t)row*2560 + c] = emb[idx];
}

// mean_feat (128 rows of 204): cols [0,102)=avgpool(att_tempo), [102,204)=avgpool(att_motion)
__global__ void avgpool_kernel(const float* __restrict__ tempo, const float* __restrict__ motion,
                               float* __restrict__ mf)
{
  int bx = blockIdx.x;          // b*8 + s
  int c = threadIdx.x;
  if (c >= 204) return;
  int b = bx >> 3, s = bx & 7;
  const float* src = (c < 102) ? (tempo  + ((size_t)(b*80 + s*10))*1024 + c*10)
                               : (motion + ((size_t)(b*80 + s*10))*1024 + (c-102)*10);
  float acc = 0.f;
  for (int r=0;r<10;r++){
    const float* p = src + (size_t)r*1024;
#pragma unroll
    for (int cc=0;cc<10;cc++) acc += p[cc];
  }
  mf[bx*204 + c] = acc * 0.01f;
}

// m0 = mean_feat @ Wli^T + bli   (128 x 512, K=204)   fp32
__global__ __launch_bounds__(256) void m0_kernel(const float* __restrict__ mf,
    const float* __restrict__ Wli, const float* __restrict__ bli, float* __restrict__ m0)
{
  __shared__ float rowv[204];
  int bx = blockIdx.x, tid = threadIdx.x;
  if (tid < 204) rowv[tid] = mf[bx*204 + tid];
  __syncthreads();
  for (int c = tid; c < 512; c += 256){
    const float* w = Wli + (size_t)c*204;
    float acc = bli[c];
    for (int k=0;k<204;k++) acc += rowv[k]*w[k];
    m0[bx*512 + c] = acc;
  }
}

// ---------------------------------------------------------------------------
// One LSTM step. X holds precomputed x@Wih^T + bih + bhh, layout (b*Tsteps+t, 2048).
// grid (16 chunks of 32 units, 4 groups of 4 batches), 128 threads.
// Writes h/c; if finalA!=null also writes tanh(h) into finalA cols [0,512).
// ---------------------------------------------------------------------------
__global__ __launch_bounds__(128) void lstm_step_kernel(
    const float* __restrict__ X, int t, int Tsteps,
    const float* __restrict__ Whh,
    const float* __restrict__ hin, const float* __restrict__ cin,
    float* __restrict__ hout, float* __restrict__ cout,
    float* __restrict__ finalA, int first)
{
  __shared__ float hs[4][512];
  __shared__ float gbuf[4][32][4];   // [gate][unit][batch-in-group]
  int tid = threadIdx.x;
  int chunk = blockIdx.x, bg = blockIdx.y;
  for (int i = tid; i < 2048; i += 128){
    int bb = i >> 9, k = i & 511;
    hs[bb][k] = first ? 0.f : hin[(size_t)(bg*4 + bb)*512 + k];
  }
  __syncthreads();
  int g = tid >> 5, j = tid & 31;
  int u = (chunk << 5) + j;
  int row = (g << 9) + u;
  const float* wr = Whh + (size_t)row * 512;
  float a0=0,a1=0,a2=0,a3=0;
  for (int k=0;k<512;k+=4){
    float4 w  = *(const float4*)(wr + k);
    float4 h0 = *(const float4*)(&hs[0][k]);
    float4 h1 = *(const float4*)(&hs[1][k]);
    float4 h2 = *(const float4*)(&hs[2][k]);
    float4 h3 = *(const float4*)(&hs[3][k]);
    a0 += w.x*h0.x + w.y*h0.y + w.z*h0.z + w.w*h0.w;
    a1 += w.x*h1.x + w.y*h1.y + w.z*h1.z + w.w*h1.w;
    a2 += w.x*h2.x + w.y*h2.y + w.z*h2.z + w.w*h2.w;
    a3 += w.x*h3.x + w.y*h3.y + w.z*h3.z + w.w*h3.w;
  }
  gbuf[g][j][0] = a0 + X[((size_t)(bg*4+0)*Tsteps + t)*2048 + row];
  gbuf[g][j][1] = a1 + X[((size_t)(bg*4+1)*Tsteps + t)*2048 + row];
  gbuf[g][j][2] = a2 + X[((size_t)(bg*4+2)*Tsteps + t)*2048 + row];
  gbuf[g][j][3] = a3 + X[((size_t)(bg*4+3)*Tsteps + t)*2048 + row];
  __syncthreads();
  int bb = tid >> 5, j2 = tid & 31;
  int u2 = (chunk << 5) + j2;
  int b = bg*4 + bb;
  float iv = gbuf[0][j2][bb], fv = gbuf[1][j2][bb];
  float gv = gbuf[2][j2][bb], ov = gbuf[3][j2][bb];
  float cp = first ? 0.f : cin[(size_t)b*512 + u2];
  float cn = sigm(fv)*cp + sigm(iv)*tanhf(gv);
  float hn = sigm(ov)*tanhf(cn);
  hout[(size_t)b*512 + u2] = hn;
  cout[(size_t)b*512 + u2] = cn;
  if (finalA) finalA[(size_t)(b*80 + t)*2560 + u2] = tanhf(hn);
}

// out[r] = bias[0] + dot(A[r*stride .. +ncols], w)    one wave per row
__global__ void proj_kernel(const float* __restrict__ A, int stride, int ncols,
                            const float* __restrict__ w, const float* __restrict__ bias,
                            float* __restrict__ out)
{
  int r = blockIdx.x, lane = threadIdx.x;
  const float* a = A + (size_t)r * stride;
  float acc = 0.f;
  for (int c = lane; c < ncols; c += 64) acc += a[c]*w[c];
  acc = wred_sum(acc);
  if (lane == 0) out[r] = acc + (bias ? bias[0] : 0.f);
}

// softmax over l of (e[b,s] + f[b,l]) masked by l < lens[b]; rows = b*80+s
__global__ __launch_bounds__(256) void attsmax_kernel(const float* __restrict__ e,
    const float* __restrict__ f, const int* __restrict__ lens, float* __restrict__ w)
{
  __shared__ float sm[4];
  int bx = blockIdx.x;
  int b = bx / 80;
  int tid = threadIdx.x;
  int len = lens[b];
  bool ok = (tid < 200) && (tid < len);
  float val = ok ? (e[bx] + f[b*200 + tid]) : -1e30f;
  float m = bred_max(val, sm);
  float ex = ok ? __expf(val - m) : 0.f;
  float s = bred_sum(ex, sm);
  if (tid < 200) w[(size_t)bx*200 + tid] = ex / s;
}

// out[b, s, :] = sum_l w[b,s,l] * feats[b,l,:]  written into finalA at coloff
// grid (16 batches, 10 s-groups of 8), 256 threads (4 feature cols each)
__global__ __launch_bounds__(256) void attapply_kernel(const float* __restrict__ w,
    const float* __restrict__ feats, float* __restrict__ finalA, int coloff)
{
  __shared__ float lw[8][200];
  int b = blockIdx.x, sg = blockIdx.y;
  int tid = threadIdx.x;
  for (int i = tid; i < 1600; i += 256){
    int ss = i / 200, l = i - ss*200;
    lw[ss][l] = w[(size_t)(b*80 + sg*8 + ss)*200 + l];
  }
  __syncthreads();
  float4 acc[8];
#pragma unroll
  for (int s=0;s<8;s++) acc[s] = make_float4(0,0,0,0);
  const float* fb = feats + (size_t)b*200*1024 + tid*4;
  for (int l=0;l<200;l++){
    float4 v = *(const float4*)(fb + (size_t)l*1024);
#pragma unroll
    for (int s=0;s<8;s++){
      float wv = lw[s][l];
      acc[s].x += wv*v.x; acc[s].y += wv*v.y; acc[s].z += wv*v.z; acc[s].w += wv*v.w;
    }
  }
#pragma unroll
  for (int s=0;s<8;s++){
    float* o = finalA + (size_t)(b*80 + sg*8 + s)*2560 + coloff + tid*4;
    *(float4*)o = acc[s];
  }
}

// in-place log_softmax over rows of 10000
__global__ __launch_bounds__(256) void logsmax_kernel(float* __restrict__ out)
{
  __shared__ float buf[10000];
  __shared__ float sm[4];
  int row = blockIdx.x, tid = threadIdx.x;
  float* o = out + (size_t)row * 10000;
  float m = -1e30f;
  for (int i = tid; i < 10000; i += 256){ float v = o[i]; buf[i] = v; m = fmaxf(m, v); }
  m = bred_max(m, sm);
  float s = 0.f;
  for (int i = tid; i < 10000; i += 256) s += __expf(buf[i] - m);
  s = bred_sum(s, sm);
  float lse = m + __logf(s);
  for (int i = tid; i < 10000; i += 256) o[i] = buf[i] - lse;
}

// ---------------------------------------------------------------------------
extern "C" void kernel_launch(void* const* d_in, const int* in_sizes, int n_in,
                              void* d_out, int out_size, void* d_ws, size_t ws_size,
                              hipStream_t stream)
{
  const float* mfeat = (const float*)d_in[0];
  const float* tfeat = (const float*)d_in[1];
  const float* attm  = (const float*)d_in[2];
  const float* attt  = (const float*)d_in[3];
  const float* emb   = (const float*)d_in[4];
  const int* lens_m  = (const int*)d_in[5];
  const int* lens_t  = (const int*)d_in[6];
  const float* Wm  = (const float*)d_in[8];
  const float* bm  = (const float*)d_in[9];
  const float* Wt  = (const float*)d_in[10];
  const float* bt  = (const float*)d_in[11];
  const float* Wmm = (const float*)d_in[12];
  const float* bmm = (const float*)d_in[13];
  const float* Wli = (const float*)d_in[14];
  const float* bli = (const float*)d_in[15];
  const float* Wih = (const float*)d_in[16];
  const float* Whh = (const float*)d_in[17];
  const float* bih = (const float*)d_in[18];
  const float* bhh = (const float*)d_in[19];
  const float* Wsm = (const float*)d_in[20];
  const float* bsm = (const float*)d_in[21];
  const float* Wst = (const float*)d_in[22];
  const float* bst = (const float*)d_in[23];
  const float* Wo  = (const float*)d_in[24];
  const float* bo  = (const float*)d_in[25];
  float* out = (float*)d_out;

  char* ws = (char*)d_ws;
  size_t off = 0;
  auto alloc = [&](size_t bytes)->float* {
    float* p = (float*)(ws + off);
    off += (bytes + 255) & ~(size_t)255;
    return p;
  };
  float* mm_inp = alloc(1280UL*2560*4);   // concat(emb, tout, mout) f32
  float* finalA = alloc(1280UL*2560*4);   // concat(act, att_t2, att_m2) f32
  float* moutp  = alloc(1280UL*1024*4);
  float* toutp  = alloc(1280UL*1024*4);
  float* mm_out = alloc(1280UL*512*4);
  float* meanf  = alloc(128UL*204*4);
  float* m0     = alloc(128UL*512*4);
  float* X1     = alloc(128UL*2048*4);
  float* X2     = alloc(1280UL*2048*4);
  float* hb0 = alloc(16UL*512*4); float* hb1 = alloc(16UL*512*4);
  float* cb0 = alloc(16UL*512*4); float* cb1 = alloc(16UL*512*4);
  float* hb[2] = { hb0, hb1 };
  float* cb[2] = { cb0, cb1 };
  float* e_m = alloc(1280UL*4); float* e_t = alloc(1280UL*4);
  float* f_m = alloc(3200UL*4); float* f_t = alloc(3200UL*4);
  float* w_m = alloc(1280UL*200*4); float* w_t = alloc(1280UL*200*4);

  // temp_mout / temp_tout pre-activations
  gemm_bf16_kernel<<<dim3(16, 20), 256, 0, stream>>>(attm, Wm, bm, nullptr, moutp, 1024, 1024);
  gemm_bf16_kernel<<<dim3(16, 20), 256, 0, stream>>>(attt, Wt, bt, nullptr, toutp, 1024, 1024);
  // x * softmax(x) straight into mm_inp columns; emb copied into cols [0,512)
  rowsmx_kernel<<<1280, 256, 0, stream>>>(moutp, mm_inp, 2560, 1536);
  rowsmx_kernel<<<1280, 256, 0, stream>>>(toutp, mm_inp, 2560, 512);
  embcopy_kernel<<<(1280*512 + 255)/256, 256, 0, stream>>>(emb, mm_inp);
  // mm_out = mm_inp @ Wmm^T + bmm
  gemm_bf16_kernel<<<dim3(8, 20), 256, 0, stream>>>(mm_inp, Wmm, bmm, nullptr, mm_out, 512, 2560);
  // avgpool + m0
  avgpool_kernel<<<128, 256, 0, stream>>>(attt, attm, meanf);
  m0_kernel<<<128, 256, 0, stream>>>(meanf, Wli, bli, m0);
  // gate preactivations (x-part) for both LSTMs
  gemm_bf16_kernel<<<dim3(32, 2), 256, 0, stream>>>(m0, Wih, bih, bhh, X1, 2048, 512);
  gemm_bf16_kernel<<<dim3(32, 20), 256, 0, stream>>>(mm_out, Wih, bih, bhh, X2, 2048, 512);
  // LSTM 1 (8 steps, zero init) then LSTM 2 (80 steps, writes act into finalA)
  int p = 0;
  for (int t = 0; t < 8; t++){
    lstm_step_kernel<<<dim3(16,4), 128, 0, stream>>>(X1, t, 8, Whh,
        hb[p], cb[p], hb[1-p], cb[1-p], nullptr, t == 0 ? 1 : 0);
    p = 1 - p;
  }
  for (int t = 0; t < 80; t++){
    lstm_step_kernel<<<dim3(16,4), 128, 0, stream>>>(X2, t, 80, Whh,
        hb[p], cb[p], hb[1-p], cb[1-p], finalA, 0);
    p = 1 - p;
  }
  // attention score pieces
  proj_kernel<<<1280, 64, 0, stream>>>(finalA, 2560, 512, Wsm, bsm, e_m);
  proj_kernel<<<3200, 64, 0, stream>>>(mfeat, 1024, 1024, Wsm + 512, nullptr, f_m);
  proj_kernel<<<1280, 64, 0, stream>>>(finalA, 2560, 512, Wst, bst, e_t);
  proj_kernel<<<3200, 64, 0, stream>>>(tfeat, 1024, 1024, Wst + 512, nullptr, f_t);
  attsmax_kernel<<<1280, 256, 0, stream>>>(e_t, f_t, lens_t, w_t);
  attsmax_kernel<<<1280, 256, 0, stream>>>(e_m, f_m, lens_m, w_m);
  // weighted sums into finalA cols: att_t2 -> [512,1536), att_m2 -> [1536,2560)
  attapply_kernel<<<dim3(16,10), 256, 0, stream>>>(w_t, tfeat, finalA, 512);
  attapply_kernel<<<dim3(16,10), 256, 0, stream>>>(w_m, mfeat, finalA, 1536);
  // final = finalA @ Wo^T + bo, then in-place log_softmax
  gemm_bf16_kernel<<<dim3((10000 + 63)/64, 20), 256, 0, stream>>>(finalA, Wo, bo, nullptr, out, 10000, 2560);
  logsmax_kernel<<<1280, 256, 0, stream>>>(out);
}

// Round 2
// 2332.662 us; speedup vs baseline: 1.3245x; 1.3245x over previous
//
#include <hip/hip_runtime.h>
#include <hip/hip_bf16.h>
#include <math.h>

// Dims: E=512 M=1024 T=1024 H=512 V=10000 ; B=16 S=80 L=200 ; K=10

typedef __bf16 bf16x8 __attribute__((ext_vector_type(8)));
typedef float f32x4 __attribute__((ext_vector_type(4)));
typedef unsigned short u16x8 __attribute__((ext_vector_type(8)));

__device__ inline unsigned short f2b(float f){
  union { float f; unsigned u; } v; v.f = f;
  unsigned u = v.u;
  u += 0x7fff + ((u >> 16) & 1);       // round-to-nearest-even
  return (unsigned short)(u >> 16);
}
__device__ inline float sigm(float x){ return 1.f/(1.f + __expf(-x)); }
__device__ inline float wred_max(float v){ for (int o=32;o;o>>=1) v = fmaxf(v, __shfl_xor(v,o)); return v; }
__device__ inline float wred_sum(float v){ for (int o=32;o;o>>=1) v += __shfl_xor(v,o); return v; }

__device__ inline float bred_max(float v, float* sm){
  v = wred_max(v);
  int w = threadIdx.x >> 6;
  if ((threadIdx.x & 63) == 0) sm[w] = v;
  __syncthreads();
  v = fmaxf(fmaxf(sm[0], sm[1]), fmaxf(sm[2], sm[3]));
  __syncthreads();
  return v;
}
__device__ inline float bred_sum(float v, float* sm){
  v = wred_sum(v);
  int w = threadIdx.x >> 6;
  if ((threadIdx.x & 63) == 0) sm[w] = v;
  __syncthreads();
  v = sm[0] + sm[1] + sm[2] + sm[3];
  __syncthreads();
  return v;
}

#define GLOAD_LDS16(g, l) __builtin_amdgcn_global_load_lds( \
    (const __attribute__((address_space(1))) void*)(g), \
    (__attribute__((address_space(3))) void*)(l), 16, 0, 0)

// ---------------------------------------------------------------------------
// f32 -> bf16 conversion, 8 elems/thread
// ---------------------------------------------------------------------------
__global__ void cvt_bf16_kernel(const float* __restrict__ s, unsigned short* __restrict__ d, int n8){
  int i = blockIdx.x*256 + threadIdx.x;
  if (i >= n8) return;
  float4 a = ((const float4*)s)[i*2];
  float4 b = ((const float4*)s)[i*2+1];
  u16x8 o;
  o[0]=f2b(a.x); o[1]=f2b(a.y); o[2]=f2b(a.z); o[3]=f2b(a.w);
  o[4]=f2b(b.x); o[5]=f2b(b.y); o[6]=f2b(b.z); o[7]=f2b(b.w);
  ((u16x8*)d)[i] = o;
}

// ---------------------------------------------------------------------------
// C = A @ B^T + b1 + b2.  A:(R,K) bf16 row-major, B:(N,K) bf16 row-major,
// C:(R,N) f32.  128x128 tile, BK=32, 256 thr (4 waves, 2x2 of 64x64).
// grid = (R/128, ceil(N/128)); R%128==0, K%32==0. global_load_lds staging.
// ---------------------------------------------------------------------------
__global__ __launch_bounds__(256) void gemm_bb_kernel(
    const unsigned short* __restrict__ A, const unsigned short* __restrict__ B,
    const float* __restrict__ bias1, const float* __restrict__ bias2,
    float* __restrict__ C, int N, int K)
{
  __shared__ unsigned short lA[128*32];
  __shared__ unsigned short lB[128*32];
  int tid = threadIdx.x;
  int r0 = blockIdx.x << 7, n0 = blockIdx.y << 7;
  int w = tid >> 6, lane = tid & 63;
  int wr = (w >> 1) << 6, wc = (w & 1) << 6;
  int lm = lane & 15, lq = lane >> 4;
  f32x4 acc[4][4] = {};

  // staging chunk c -> LDS row-major (row = c>>2, 16B chunk = c&3)
  int row0 = tid >> 2, row1 = (tid + 256) >> 2, cc = (tid & 3) << 3;
  const unsigned short* Ag0 = A + (size_t)(r0 + row0)*K + cc;
  const unsigned short* Ag1 = A + (size_t)(r0 + row1)*K + cc;
  int br0 = n0 + row0; if (br0 >= N) br0 = N - 1;
  int br1 = n0 + row1; if (br1 >= N) br1 = N - 1;
  const unsigned short* Bg0 = B + (size_t)br0*K + cc;
  const unsigned short* Bg1 = B + (size_t)br1*K + cc;
  unsigned lb0 = (unsigned)(tid & ~63) * 8;   // u16 index, wave-uniform
  unsigned lb1 = 2048 + lb0;

  for (int k0 = 0; k0 < K; k0 += 32){
    GLOAD_LDS16(Ag0 + k0, &lA[lb0]);
    GLOAD_LDS16(Ag1 + k0, &lA[lb1]);
    GLOAD_LDS16(Bg0 + k0, &lB[lb0]);
    GLOAD_LDS16(Bg1 + k0, &lB[lb1]);
    __syncthreads();
    bf16x8 af[4], bfr[4];
#pragma unroll
    for (int i=0;i<4;i++){
      af[i]  = *(const bf16x8*)&lA[(wr + i*16 + lm)*32 + lq*8];
      bfr[i] = *(const bf16x8*)&lB[(wc + i*16 + lm)*32 + lq*8];
    }
#pragma unroll
    for (int i=0;i<4;i++)
#pragma unroll
      for (int j=0;j<4;j++)
        acc[i][j] = __builtin_amdgcn_mfma_f32_16x16x32_bf16(af[i], bfr[j], acc[i][j], 0, 0, 0);
    __syncthreads();
  }
  // C/D layout: col = lane&15, row = (lane>>4)*4 + reg
#pragma unroll
  for (int i=0;i<4;i++){
    int rbase = r0 + wr + i*16 + lq*4;
#pragma unroll
    for (int j=0;j<4;j++){
      int n = n0 + wc + j*16 + lm;
      if (n < N){
        float bv = (bias1 ? bias1[n] : 0.f) + (bias2 ? bias2[n] : 0.f);
#pragma unroll
        for (int rr=0;rr<4;rr++)
          C[(size_t)(rbase + rr)*N + n] = acc[i][j][rr] + bv;
      }
    }
  }
}

// ---------------------------------------------------------------------------
// y = x * softmax(x) over rows of 1024; writes bf16 into out[row*ostride+ooff+i]
// ---------------------------------------------------------------------------
__global__ __launch_bounds__(256) void rowsmx_kernel(const float* __restrict__ X,
    unsigned short* __restrict__ out, int ostride, int ooff)
{
  __shared__ float sm[4];
  int row = blockIdx.x, tid = threadIdx.x;
  const float* xr = X + (size_t)row * 1024;
  float x[4];
#pragma unroll
  for (int j=0;j<4;j++) x[j] = xr[j*256 + tid];
  float m = fmaxf(fmaxf(x[0],x[1]), fmaxf(x[2],x[3]));
  m = bred_max(m, sm);
  float s = 0.f;
#pragma unroll
  for (int j=0;j<4;j++) s += __expf(x[j]-m);
  s = bred_sum(s, sm);
  float inv = 1.f / s;
  unsigned short* o = out + (size_t)row*ostride + ooff;
#pragma unroll
  for (int j=0;j<4;j++) o[j*256 + tid] = f2b(x[j] * (__expf(x[j]-m) * inv));
}

// emb f32 (1280x512) -> bf16 into mm_inp_bf cols [0,512)
__global__ void embcopy_kernel(const float* __restrict__ emb, unsigned short* __restrict__ mmbf){
  int idx = blockIdx.x*256 + threadIdx.x;        // 8-elem chunks
  if (idx >= 1280*64) return;
  int row = idx >> 6, c8 = (idx & 63) << 3;
  const float* s = emb + (size_t)row*512 + c8;
  float4 a = ((const float4*)s)[0], b = ((const float4*)s)[1];
  u16x8 o;
  o[0]=f2b(a.x); o[1]=f2b(a.y); o[2]=f2b(a.z); o[3]=f2b(a.w);
  o[4]=f2b(b.x); o[5]=f2b(b.y); o[6]=f2b(b.z); o[7]=f2b(b.w);
  *(u16x8*)&mmbf[(size_t)row*2560 + c8] = o;
}

// mean_feat (128 rows of 204): cols [0,102)=avgpool(att_tempo), [102,204)=avgpool(att_motion)
__global__ void avgpool_kernel(const float* __restrict__ tempo, const float* __restrict__ motion,
                               float* __restrict__ mf)
{
  int bx = blockIdx.x;          // b*8 + s
  int c = threadIdx.x;
  if (c >= 204) return;
  int b = bx >> 3, s = bx & 7;
  const float* src = (c < 102) ? (tempo  + ((size_t)(b*80 + s*10))*1024 + c*10)
                               : (motion + ((size_t)(b*80 + s*10))*1024 + (c-102)*10);
  float acc = 0.f;
  for (int r=0;r<10;r++){
    const float* p = src + (size_t)r*1024;
#pragma unroll
    for (int cc=0;cc<10;cc++) acc += p[cc];
  }
  mf[bx*204 + c] = acc * 0.01f;
}

// m0 = mean_feat @ Wli^T + bli   (128 x 512, K=204)   fp32
__global__ __launch_bounds__(256) void m0_kernel(const float* __restrict__ mf,
    const float* __restrict__ Wli, const float* __restrict__ bli, float* __restrict__ m0)
{
  __shared__ float rowv[204];
  int bx = blockIdx.x, tid = threadIdx.x;
  if (tid < 204) rowv[tid] = mf[bx*204 + tid];
  __syncthreads();
  for (int c = tid; c < 512; c += 256){
    const float* w = Wli + (size_t)c*204;
    float acc = bli[c];
    for (int k=0;k<204;k++) acc += rowv[k]*w[k];
    m0[bx*512 + c] = acc;
  }
}

// ---------------------------------------------------------------------------
// One LSTM step, all 16 batches per block. grid = 32 blocks (16 units each),
// 256 threads: thread = (batch-quad q = tid>>6) x (local row r = tid&63).
// Local row r -> gate g=r>>4, unit ul=r&15, global row g*512 + blk*16 + ul.
// Whh traffic: 4 MB/step total (each row read once). X = precomputed
// x@Wih^T + bih + bhh, rows (b*Tsteps + t).
// ---------------------------------------------------------------------------
__global__ __launch_bounds__(256) void lstm_step_kernel(
    const float* __restrict__ X, int t, int Tsteps,
    const float* __restrict__ Whh,
    const float* __restrict__ hin, float* __restrict__ hout,
    float* __restrict__ cio, float* __restrict__ finalA, int first)
{
  __shared__ float hs[16][512];     // full h, 32 KB
  __shared__ float gb[4][16][16];   // [gate][unit][batch]
  int tid = threadIdx.x, j = blockIdx.x;
  if (first){
    for (int i = tid; i < 2048; i += 256) ((float4*)hs)[i] = make_float4(0,0,0,0);
  } else {
    for (int i = tid; i < 2048; i += 256) ((float4*)hs)[i] = ((const float4*)hin)[i];
  }
  __syncthreads();
  int r = tid & 63, q = tid >> 6;
  int g = r >> 4, ul = r & 15;
  int grow = g*512 + j*16 + ul;
  const float* wr = Whh + (size_t)grow*512;
  const float* h0 = hs[q*4+0];
  const float* h1 = hs[q*4+1];
  const float* h2 = hs[q*4+2];
  const float* h3 = hs[q*4+3];
  float a0=0.f, a1=0.f, a2=0.f, a3=0.f;
#pragma unroll 4
  for (int k=0;k<512;k+=4){
    float4 wv = *(const float4*)(wr + k);
    float4 x0 = *(const float4*)(h0 + k);
    float4 x1 = *(const float4*)(h1 + k);
    float4 x2 = *(const float4*)(h2 + k);
    float4 x3 = *(const float4*)(h3 + k);
    a0 += wv.x*x0.x + wv.y*x0.y + wv.z*x0.z + wv.w*x0.w;
    a1 += wv.x*x1.x + wv.y*x1.y + wv.z*x1.z + wv.w*x1.w;
    a2 += wv.x*x2.x + wv.y*x2.y + wv.z*x2.z + wv.w*x2.w;
    a3 += wv.x*x3.x + wv.y*x3.y + wv.z*x3.z + wv.w*x3.w;
  }
  size_t xb = ((size_t)(q*4)*Tsteps + t)*2048 + grow;
  size_t xs = (size_t)Tsteps*2048;
  gb[g][ul][q*4+0] = a0 + X[xb];
  gb[g][ul][q*4+1] = a1 + X[xb + xs];
  gb[g][ul][q*4+2] = a2 + X[xb + 2*xs];
  gb[g][ul][q*4+3] = a3 + X[xb + 3*xs];
  __syncthreads();
  int b = tid >> 4, u2 = tid & 15, uu = j*16 + u2;
  float iv = gb[0][u2][b], fv = gb[1][u2][b];
  float gv = gb[2][u2][b], ov = gb[3][u2][b];
  float cp = first ? 0.f : cio[b*512 + uu];
  float cn = sigm(fv)*cp + sigm(iv)*tanhf(gv);
  float hn = sigm(ov)*tanhf(cn);
  cio[b*512 + uu] = cn;
  hout[b*512 + uu] = hn;
  if (finalA) finalA[(size_t)(b*80 + t)*2560 + uu] = tanhf(hn);
}

// out[r] = bias[0] + dot(A[r*stride .. +ncols], w)    one wave per row
__global__ void proj_kernel(const float* __restrict__ A, int stride, int ncols,
                            const float* __restrict__ w, const float* __restrict__ bias,
                            float* __restrict__ out)
{
  int r = blockIdx.x, lane = threadIdx.x;
  const float* a = A + (size_t)r * stride;
  float acc = 0.f;
  for (int c = lane; c < ncols; c += 64) acc += a[c]*w[c];
  acc = wred_sum(acc);
  if (lane == 0) out[r] = acc + (bias ? bias[0] : 0.f);
}

// softmax over l of (e[b,s] + f[b,l]) masked by l < lens[b]; rows = b*80+s
__global__ __launch_bounds__(256) void attsmax_kernel(const float* __restrict__ e,
    const float* __restrict__ f, const int* __restrict__ lens, float* __restrict__ w)
{
  __shared__ float sm[4];
  int bx = blockIdx.x;
  int b = bx / 80;
  int tid = threadIdx.x;
  int len = lens[b];
  bool ok = (tid < 200) && (tid < len);
  float val = ok ? (e[bx] + f[b*200 + tid]) : -1e30f;
  float m = bred_max(val, sm);
  float ex = ok ? __expf(val - m) : 0.f;
  float s = bred_sum(ex, sm);
  if (tid < 200) w[(size_t)bx*200 + tid] = ex / s;
}

// out[b, s, :] = sum_l w[b,s,l] * feats[b,l,:]  written into finalA at coloff
__global__ __launch_bounds__(256) void attapply_kernel(const float* __restrict__ w,
    const float* __restrict__ feats, float* __restrict__ finalA, int coloff)
{
  __shared__ float lw[8][200];
  int b = blockIdx.x, sg = blockIdx.y;
  int tid = threadIdx.x;
  for (int i = tid; i < 1600; i += 256){
    int ss = i / 200, l = i - ss*200;
    lw[ss][l] = w[(size_t)(b*80 + sg*8 + ss)*200 + l];
  }
  __syncthreads();
  float4 acc[8];
#pragma unroll
  for (int s=0;s<8;s++) acc[s] = make_float4(0,0,0,0);
  const float* fb = feats + (size_t)b*200*1024 + tid*4;
  for (int l=0;l<200;l++){
    float4 v = *(const float4*)(fb + (size_t)l*1024);
#pragma unroll
    for (int s=0;s<8;s++){
      float wv = lw[s][l];
      acc[s].x += wv*v.x; acc[s].y += wv*v.y; acc[s].z += wv*v.z; acc[s].w += wv*v.w;
    }
  }
#pragma unroll
  for (int s=0;s<8;s++){
    float* o = finalA + (size_t)(b*80 + sg*8 + s)*2560 + coloff + tid*4;
    *(float4*)o = acc[s];
  }
}

// in-place log_softmax over rows of 10000
__global__ __launch_bounds__(256) void logsmax_kernel(float* __restrict__ out)
{
  __shared__ float buf[10000];
  __shared__ float sm[4];
  int row = blockIdx.x, tid = threadIdx.x;
  float* o = out + (size_t)row * 10000;
  float m = -1e30f;
  for (int i = tid; i < 10000; i += 256){ float v = o[i]; buf[i] = v; m = fmaxf(m, v); }
  m = bred_max(m, sm);
  float s = 0.f;
  for (int i = tid; i < 10000; i += 256) s += __expf(buf[i] - m);
  s = bred_sum(s, sm);
  float lse = m + __logf(s);
  for (int i = tid; i < 10000; i += 256) o[i] = buf[i] - lse;
}

// ---------------------------------------------------------------------------
extern "C" void kernel_launch(void* const* d_in, const int* in_sizes, int n_in,
                              void* d_out, int out_size, void* d_ws, size_t ws_size,
                              hipStream_t stream)
{
  const float* mfeat = (const float*)d_in[0];
  const float* tfeat = (const float*)d_in[1];
  const float* attm  = (const float*)d_in[2];
  const float* attt  = (const float*)d_in[3];
  const float* emb   = (const float*)d_in[4];
  const int* lens_m  = (const int*)d_in[5];
  const int* lens_t  = (const int*)d_in[6];
  const float* Wm  = (const float*)d_in[8];
  const float* bm  = (const float*)d_in[9];
  const float* Wt  = (const float*)d_in[10];
  const float* bt  = (const float*)d_in[11];
  const float* Wmm = (const float*)d_in[12];
  const float* bmm = (const float*)d_in[13];
  const float* Wli = (const float*)d_in[14];
  const float* bli = (const float*)d_in[15];
  const float* Wih = (const float*)d_in[16];
  const float* Whh = (const float*)d_in[17];
  const float* bih = (const float*)d_in[18];
  const float* bhh = (const float*)d_in[19];
  const float* Wsm = (const float*)d_in[20];
  const float* bsm = (const float*)d_in[21];
  const float* Wst = (const float*)d_in[22];
  const float* bst = (const float*)d_in[23];
  const float* Wo  = (const float*)d_in[24];
  const float* bo  = (const float*)d_in[25];
  float* out = (float*)d_out;

  char* ws = (char*)d_ws;
  size_t off = 0;
  auto alloc = [&](size_t bytes)->void* {
    void* p = (void*)(ws + off);
    off += (bytes + 255) & ~(size_t)255;
    return p;
  };
  // f32 scratch
  float* finalA = (float*)alloc(1280UL*2560*4);
  float* moutp  = (float*)alloc(1280UL*1024*4);
  float* toutp  = (float*)alloc(1280UL*1024*4);
  float* mm_out = (float*)alloc(1280UL*512*4);
  float* meanf  = (float*)alloc(128UL*204*4);
  float* m0     = (float*)alloc(128UL*512*4);
  float* X1     = (float*)alloc(128UL*2048*4);
  float* X2     = (float*)alloc(1280UL*2048*4);
  float* hb0 = (float*)alloc(16UL*512*4); float* hb1 = (float*)alloc(16UL*512*4);
  float* cio = (float*)alloc(16UL*512*4);
  float* hb[2] = { hb0, hb1 };
  float* e_m = (float*)alloc(1280UL*4); float* e_t = (float*)alloc(1280UL*4);
  float* f_m = (float*)alloc(3200UL*4); float* f_t = (float*)alloc(3200UL*4);
  float* w_m = (float*)alloc(1280UL*200*4); float* w_t = (float*)alloc(1280UL*200*4);
  // bf16 scratch
  unsigned short* attm_bf   = (unsigned short*)alloc(1280UL*1024*2);
  unsigned short* attt_bf   = (unsigned short*)alloc(1280UL*1024*2);
  unsigned short* Wm_bf     = (unsigned short*)alloc(1024UL*1024*2);
  unsigned short* Wt_bf     = (unsigned short*)alloc(1024UL*1024*2);
  unsigned short* Wmm_bf    = (unsigned short*)alloc(512UL*2560*2);
  unsigned short* Wih_bf    = (unsigned short*)alloc(2048UL*512*2);
  unsigned short* Wo_bf     = (unsigned short*)alloc(10000UL*2560*2);
  unsigned short* mm_inp_bf = (unsigned short*)alloc(1280UL*2560*2);
  unsigned short* mm_out_bf = (unsigned short*)alloc(1280UL*512*2);
  unsigned short* m0_bf     = (unsigned short*)alloc(128UL*512*2);
  unsigned short* finalA_bf = (unsigned short*)alloc(1280UL*2560*2);

  auto cvt = [&](const float* s, unsigned short* d, size_t n){
    int n8 = (int)(n/8);
    cvt_bf16_kernel<<<(n8 + 255)/256, 256, 0, stream>>>(s, d, n8);
  };
  // weight + input conversions
  cvt(attm, attm_bf, 1280UL*1024);
  cvt(attt, attt_bf, 1280UL*1024);
  cvt(Wm,  Wm_bf,  1024UL*1024);
  cvt(Wt,  Wt_bf,  1024UL*1024);
  cvt(Wmm, Wmm_bf, 512UL*2560);
  cvt(Wih, Wih_bf, 2048UL*512);
  cvt(Wo,  Wo_bf,  10000UL*2560);

  // temp_mout / temp_tout pre-activations
  gemm_bb_kernel<<<dim3(10, 8), 256, 0, stream>>>(attm_bf, Wm_bf, bm, nullptr, moutp, 1024, 1024);
  gemm_bb_kernel<<<dim3(10, 8), 256, 0, stream>>>(attt_bf, Wt_bf, bt, nullptr, toutp, 1024, 1024);
  // x * softmax(x) -> bf16 straight into mm_inp columns; emb -> cols [0,512)
  rowsmx_kernel<<<1280, 256, 0, stream>>>(moutp, mm_inp_bf, 2560, 1536);
  rowsmx_kernel<<<1280, 256, 0, stream>>>(toutp, mm_inp_bf, 2560, 512);
  embcopy_kernel<<<(1280*64 + 255)/256, 256, 0, stream>>>(emb, mm_inp_bf);
  // mm_out = mm_inp @ Wmm^T + bmm
  gemm_bb_kernel<<<dim3(10, 4), 256, 0, stream>>>(mm_inp_bf, Wmm_bf, bmm, nullptr, mm_out, 512, 2560);
  cvt(mm_out, mm_out_bf, 1280UL*512);
  // avgpool + m0
  avgpool_kernel<<<128, 256, 0, stream>>>(attt, attm, meanf);
  m0_kernel<<<128, 256, 0, stream>>>(meanf, Wli, bli, m0);
  cvt(m0, m0_bf, 128UL*512);
  // gate preactivations (x-part) for both LSTMs
  gemm_bb_kernel<<<dim3(1, 16), 256, 0, stream>>>(m0_bf, Wih_bf, bih, bhh, X1, 2048, 512);
  gemm_bb_kernel<<<dim3(10, 16), 256, 0, stream>>>(mm_out_bf, Wih_bf, bih, bhh, X2, 2048, 512);
  // LSTM 1 (8 steps, zero init) then LSTM 2 (80 steps, writes act into finalA)
  int p = 0;
  for (int t = 0; t < 8; t++){
    lstm_step_kernel<<<32, 256, 0, stream>>>(X1, t, 8, Whh,
        hb[p], hb[1-p], cio, nullptr, t == 0 ? 1 : 0);
    p = 1 - p;
  }
  for (int t = 0; t < 80; t++){
    lstm_step_kernel<<<32, 256, 0, stream>>>(X2, t, 80, Whh,
        hb[p], hb[1-p], cio, finalA, 0);
    p = 1 - p;
  }
  // attention score pieces
  proj_kernel<<<1280, 64, 0, stream>>>(finalA, 2560, 512, Wsm, bsm, e_m);
  proj_kernel<<<3200, 64, 0, stream>>>(mfeat, 1024, 1024, Wsm + 512, nullptr, f_m);
  proj_kernel<<<1280, 64, 0, stream>>>(finalA, 2560, 512, Wst, bst, e_t);
  proj_kernel<<<3200, 64, 0, stream>>>(tfeat, 1024, 1024, Wst + 512, nullptr, f_t);
  attsmax_kernel<<<1280, 256, 0, stream>>>(e_t, f_t, lens_t, w_t);
  attsmax_kernel<<<1280, 256, 0, stream>>>(e_m, f_m, lens_m, w_m);
  // weighted sums into finalA cols: att_t2 -> [512,1536), att_m2 -> [1536,2560)
  attapply_kernel<<<dim3(16,10), 256, 0, stream>>>(w_t, tfeat, finalA, 512);
  attapply_kernel<<<dim3(16,10), 256, 0, stream>>>(w_m, mfeat, finalA, 1536);
  // final = finalA @ Wo^T + bo, then in-place log_softmax
  cvt(finalA, finalA_bf, 1280UL*2560);
  gemm_bb_kernel<<<dim3(10, 79), 256, 0, stream>>>(finalA_bf, Wo_bf, bo, nullptr, out, 10000, 2560);
  logsmax_kernel<<<1280, 256, 0, stream>>>(out);
}

// Round 3
// 1304.746 us; speedup vs baseline: 2.3680x; 1.7878x over previous
//
#include <hip/hip_runtime.h>
#include <hip/hip_bf16.h>
#include <math.h>

// Dims: E=512 M=1024 T=1024 H=512 V=10000 ; B=16 S=80 L=200 ; K=10

typedef __bf16 bf16x8 __attribute__((ext_vector_type(8)));
typedef float f32x4 __attribute__((ext_vector_type(4)));
typedef unsigned short u16x8 __attribute__((ext_vector_type(8)));

__device__ inline unsigned short f2b(float f){
  union { float f; unsigned u; } v; v.f = f;
  unsigned u = v.u;
  u += 0x7fff + ((u >> 16) & 1);       // round-to-nearest-even
  return (unsigned short)(u >> 16);
}
__device__ inline float sigm(float x){ return 1.f/(1.f + __expf(-x)); }
__device__ inline float wred_max(float v){ for (int o=32;o;o>>=1) v = fmaxf(v, __shfl_xor(v,o)); return v; }
__device__ inline float wred_sum(float v){ for (int o=32;o;o>>=1) v += __shfl_xor(v,o); return v; }

__device__ inline float bred_max(float v, float* sm){
  v = wred_max(v);
  int w = threadIdx.x >> 6;
  if ((threadIdx.x & 63) == 0) sm[w] = v;
  __syncthreads();
  v = fmaxf(fmaxf(sm[0], sm[1]), fmaxf(sm[2], sm[3]));
  __syncthreads();
  return v;
}
__device__ inline float bred_sum(float v, float* sm){
  v = wred_sum(v);
  int w = threadIdx.x >> 6;
  if ((threadIdx.x & 63) == 0) sm[w] = v;
  __syncthreads();
  v = sm[0] + sm[1] + sm[2] + sm[3];
  __syncthreads();
  return v;
}

#define GLOAD_LDS16(g, l) __builtin_amdgcn_global_load_lds( \
    (const __attribute__((address_space(1))) void*)(g), \
    (__attribute__((address_space(3))) void*)(l), 16, 0, 0)

// ---------------------------------------------------------------------------
// f32 -> bf16 conversion, 8 elems/thread
// ---------------------------------------------------------------------------
__global__ void cvt_bf16_kernel(const float* __restrict__ s, unsigned short* __restrict__ d, int n8){
  int i = blockIdx.x*256 + threadIdx.x;
  if (i >= n8) return;
  float4 a = ((const float4*)s)[i*2];
  float4 b = ((const float4*)s)[i*2+1];
  u16x8 o;
  o[0]=f2b(a.x); o[1]=f2b(a.y); o[2]=f2b(a.z); o[3]=f2b(a.w);
  o[4]=f2b(b.x); o[5]=f2b(b.y); o[6]=f2b(b.z); o[7]=f2b(b.w);
  ((u16x8*)d)[i] = o;
}

__global__ void zero_kernel(int* p, int n){
  int i = blockIdx.x*64 + threadIdx.x;
  if (i < n) p[i] = 0;
}

// ---------------------------------------------------------------------------
// C = A @ B^T + b1 + b2.  A:(R,K) bf16 row-major, B:(N,K) bf16 row-major,
// C:(R,N) f32.  128x128 tile, BK=32, 256 thr (4 waves, 2x2 of 64x64).
// grid = (R/128, ceil(N/128)); R%128==0, K%32==0. global_load_lds staging.
// ---------------------------------------------------------------------------
__global__ __launch_bounds__(256) void gemm_bb_kernel(
    const unsigned short* __restrict__ A, const unsigned short* __restrict__ B,
    const float* __restrict__ bias1, const float* __restrict__ bias2,
    float* __restrict__ C, int N, int K)
{
  __shared__ unsigned short lA[128*32];
  __shared__ unsigned short lB[128*32];
  int tid = threadIdx.x;
  int r0 = blockIdx.x << 7, n0 = blockIdx.y << 7;
  int w = tid >> 6, lane = tid & 63;
  int wr = (w >> 1) << 6, wc = (w & 1) << 6;
  int lm = lane & 15, lq = lane >> 4;
  f32x4 acc[4][4] = {};

  int row0 = tid >> 2, row1 = (tid + 256) >> 2, cc = (tid & 3) << 3;
  const unsigned short* Ag0 = A + (size_t)(r0 + row0)*K + cc;
  const unsigned short* Ag1 = A + (size_t)(r0 + row1)*K + cc;
  int br0 = n0 + row0; if (br0 >= N) br0 = N - 1;
  int br1 = n0 + row1; if (br1 >= N) br1 = N - 1;
  const unsigned short* Bg0 = B + (size_t)br0*K + cc;
  const unsigned short* Bg1 = B + (size_t)br1*K + cc;
  unsigned lb0 = (unsigned)(tid & ~63) * 8;   // u16 index, wave-uniform
  unsigned lb1 = 2048 + lb0;

  for (int k0 = 0; k0 < K; k0 += 32){
    GLOAD_LDS16(Ag0 + k0, &lA[lb0]);
    GLOAD_LDS16(Ag1 + k0, &lA[lb1]);
    GLOAD_LDS16(Bg0 + k0, &lB[lb0]);
    GLOAD_LDS16(Bg1 + k0, &lB[lb1]);
    __syncthreads();
    bf16x8 af[4], bfr[4];
#pragma unroll
    for (int i=0;i<4;i++){
      af[i]  = *(const bf16x8*)&lA[(wr + i*16 + lm)*32 + lq*8];
      bfr[i] = *(const bf16x8*)&lB[(wc + i*16 + lm)*32 + lq*8];
    }
#pragma unroll
    for (int i=0;i<4;i++)
#pragma unroll
      for (int j=0;j<4;j++)
        acc[i][j] = __builtin_amdgcn_mfma_f32_16x16x32_bf16(af[i], bfr[j], acc[i][j], 0, 0, 0);
    __syncthreads();
  }
#pragma unroll
  for (int i=0;i<4;i++){
    int rbase = r0 + wr + i*16 + lq*4;
#pragma unroll
    for (int j=0;j<4;j++){
      int n = n0 + wc + j*16 + lm;
      if (n < N){
        float bv = (bias1 ? bias1[n] : 0.f) + (bias2 ? bias2[n] : 0.f);
#pragma unroll
        for (int rr=0;rr<4;rr++)
          C[(size_t)(rbase + rr)*N + n] = acc[i][j][rr] + bv;
      }
    }
  }
}

// ---------------------------------------------------------------------------
// y = x * softmax(x) over rows of 1024; writes bf16 into out[row*ostride+ooff+i]
// ---------------------------------------------------------------------------
__global__ __launch_bounds__(256) void rowsmx_kernel(const float* __restrict__ X,
    unsigned short* __restrict__ out, int ostride, int ooff)
{
  __shared__ float sm[4];
  int row = blockIdx.x, tid = threadIdx.x;
  const float* xr = X + (size_t)row * 1024;
  float x[4];
#pragma unroll
  for (int j=0;j<4;j++) x[j] = xr[j*256 + tid];
  float m = fmaxf(fmaxf(x[0],x[1]), fmaxf(x[2],x[3]));
  m = bred_max(m, sm);
  float s = 0.f;
#pragma unroll
  for (int j=0;j<4;j++) s += __expf(x[j]-m);
  s = bred_sum(s, sm);
  float inv = 1.f / s;
  unsigned short* o = out + (size_t)row*ostride + ooff;
#pragma unroll
  for (int j=0;j<4;j++) o[j*256 + tid] = f2b(x[j] * (__expf(x[j]-m) * inv));
}

// emb f32 (1280x512) -> bf16 into mm_inp_bf cols [0,512)
__global__ void embcopy_kernel(const float* __restrict__ emb, unsigned short* __restrict__ mmbf){
  int idx = blockIdx.x*256 + threadIdx.x;        // 8-elem chunks
  if (idx >= 1280*64) return;
  int row = idx >> 6, c8 = (idx & 63) << 3;
  const float* s = emb + (size_t)row*512 + c8;
  float4 a = ((const float4*)s)[0], b = ((const float4*)s)[1];
  u16x8 o;
  o[0]=f2b(a.x); o[1]=f2b(a.y); o[2]=f2b(a.z); o[3]=f2b(a.w);
  o[4]=f2b(b.x); o[5]=f2b(b.y); o[6]=f2b(b.z); o[7]=f2b(b.w);
  *(u16x8*)&mmbf[(size_t)row*2560 + c8] = o;
}

// mean_feat (128 rows of 204): cols [0,102)=avgpool(att_tempo), [102,204)=avgpool(att_motion)
__global__ void avgpool_kernel(const float* __restrict__ tempo, const float* __restrict__ motion,
                               float* __restrict__ mf)
{
  int bx = blockIdx.x;          // b*8 + s
  int c = threadIdx.x;
  if (c >= 204) return;
  int b = bx >> 3, s = bx & 7;
  const float* src = (c < 102) ? (tempo  + ((size_t)(b*80 + s*10))*1024 + c*10)
                               : (motion + ((size_t)(b*80 + s*10))*1024 + (c-102)*10);
  float acc = 0.f;
  for (int r=0;r<10;r++){
    const float* p = src + (size_t)r*1024;
#pragma unroll
    for (int cc=0;cc<10;cc++) acc += p[cc];
  }
  mf[bx*204 + c] = acc * 0.01f;
}

// m0 = mean_feat @ Wli^T + bli   (128 x 512, K=204)   fp32
__global__ __launch_bounds__(256) void m0_kernel(const float* __restrict__ mf,
    const float* __restrict__ Wli, const float* __restrict__ bli, float* __restrict__ m0)
{
  __shared__ float rowv[204];
  int bx = blockIdx.x, tid = threadIdx.x;
  if (tid < 204) rowv[tid] = mf[bx*204 + tid];
  __syncthreads();
  for (int c = tid; c < 512; c += 256){
    const float* w = Wli + (size_t)c*204;
    float acc = bli[c];
    for (int k=0;k<204;k++) acc += rowv[k]*w[k];
    m0[bx*512 + c] = acc;
  }
}

// ---------------------------------------------------------------------------
// Persistent fused LSTM: 32 blocks x 256 thr, block j owns units [j*16, j*16+16).
// Whh slice (4 gates x 16 units = 64 rows x 512) cached in LDS as bf16 once.
// Per step: h (16x512 bf16, double-buffered in global) -> LDS; gates via
// 16x16x32 bf16 MFMA (wave w = gate w); c held in registers across all 88
// steps (LSTM2 continues from LSTM1 state). Grid barrier = agent-scope atomic.
// ---------------------------------------------------------------------------
#define LSTM_NBLK 32
#define HP 520   // padded row stride (u16 elems)

__global__ __launch_bounds__(256) void lstm_fused_kernel(
    const float* __restrict__ X1, const float* __restrict__ X2,
    const float* __restrict__ Whh,
    unsigned short* __restrict__ hb0, unsigned short* __restrict__ hb1,
    float* __restrict__ finalA, int* __restrict__ bar)
{
  __shared__ unsigned short w_lds[64*HP];   // 66560 B
  __shared__ unsigned short h_lds[16*HP];   // 16640 B
  __shared__ float gb[4][16][16];           // 4096 B
  int tid = threadIdx.x, j = blockIdx.x;
  int j16 = j*16;
  int lane = tid & 63, w = tid >> 6;
  int lm = lane & 15, lq = lane >> 4;

  // ---- preload Whh slice (rows g*512 + j16 + u), f32 -> bf16, once ----
  for (int i = 0; i < 16; i++){
    int ch = tid + i*256;              // 4096 chunks of 8
    int r = ch >> 6, c8 = (ch & 63) << 3;
    int grow = (r >> 4)*512 + j16 + (r & 15);
    const float* s = Whh + (size_t)grow*512 + c8;
    float4 a = ((const float4*)s)[0], b = ((const float4*)s)[1];
    u16x8 o;
    o[0]=f2b(a.x); o[1]=f2b(a.y); o[2]=f2b(a.z); o[3]=f2b(a.w);
    o[4]=f2b(b.x); o[5]=f2b(b.y); o[6]=f2b(b.z); o[7]=f2b(b.w);
    *(u16x8*)&w_lds[r*HP + c8] = o;
  }

  float c_reg = 0.f;
  int ul = tid & 15, bb = tid >> 4;
  unsigned short* hbufs[2] = { hb0, hb1 };
  const int wbase = ((w << 4) + lm)*HP;
  const int abase = lm*HP;
  const int koff = lq << 3;
  int sc = 0;

  for (int seg = 0; seg < 2; seg++){
    const float* Xp = seg ? X2 : X1;
    int Tst = seg ? 80 : 8;
    for (int t = 0; t < Tst; t++){
      int pr = sc & 1;
      // ---- load h state into LDS ----
      if (sc == 0){
        u16x8 z = {0,0,0,0,0,0,0,0};
        for (int i = tid; i < 1024; i += 256){
          int b = i >> 6, c8 = (i & 63) << 3;
          *(u16x8*)&h_lds[b*HP + c8] = z;
        }
      } else {
        const u16x8* src = (const u16x8*)hbufs[pr];
        for (int i = tid; i < 1024; i += 256){
          int b = i >> 6, c8 = (i & 63) << 3;
          *(u16x8*)&h_lds[b*HP + c8] = src[i];
        }
      }
      __syncthreads();
      // ---- gates: wave w computes gate w for 16 units x 16 batches ----
      f32x4 a0 = {0.f,0.f,0.f,0.f}, a1 = {0.f,0.f,0.f,0.f};
#pragma unroll
      for (int k0 = 0; k0 < 512; k0 += 64){
        bf16x8 ha = *(const bf16x8*)&h_lds[abase + k0 + koff];
        bf16x8 wa = *(const bf16x8*)&w_lds[wbase + k0 + koff];
        a0 = __builtin_amdgcn_mfma_f32_16x16x32_bf16(ha, wa, a0, 0, 0, 0);
        bf16x8 hbf = *(const bf16x8*)&h_lds[abase + k0 + 32 + koff];
        bf16x8 wbf = *(const bf16x8*)&w_lds[wbase + k0 + 32 + koff];
        a1 = __builtin_amdgcn_mfma_f32_16x16x32_bf16(hbf, wbf, a1, 0, 0, 0);
      }
      f32x4 acc = a0 + a1;
      *(f32x4*)&gb[w][lm][lq << 2] = acc;   // gb[gate][unit][batch]
      __syncthreads();
      // ---- cell update: thread = (batch bb, unit ul) ----
      size_t xrow = ((size_t)bb*Tst + t)*2048 + j16 + ul;
      float iv = gb[0][ul][bb] + Xp[xrow];
      float fv = gb[1][ul][bb] + Xp[xrow + 512];
      float gv = gb[2][ul][bb] + Xp[xrow + 1024];
      float ov = gb[3][ul][bb] + Xp[xrow + 1536];
      c_reg = sigm(fv)*c_reg + sigm(iv)*tanhf(gv);
      float hn = sigm(ov)*tanhf(c_reg);
      hbufs[1 - pr][bb*512 + j16 + ul] = f2b(hn);
      if (seg) finalA[(size_t)(bb*80 + t)*2560 + j16 + ul] = tanhf(hn);
      // ---- grid barrier ----
      sc++;
      __syncthreads();
      if (tid == 0){
        __threadfence();
        __hip_atomic_fetch_add(bar, 1, __ATOMIC_ACQ_REL, __HIP_MEMORY_SCOPE_AGENT);
        while (__hip_atomic_load(bar, __ATOMIC_ACQUIRE, __HIP_MEMORY_SCOPE_AGENT) < sc*LSTM_NBLK)
          __builtin_amdgcn_s_sleep(2);
      }
      __syncthreads();
      __threadfence();
    }
  }
}

// out[r] = bias[0] + dot(A[r*stride .. +ncols], w)    one wave per row
__global__ void proj_kernel(const float* __restrict__ A, int stride, int ncols,
                            const float* __restrict__ w, const float* __restrict__ bias,
                            float* __restrict__ out)
{
  int r = blockIdx.x, lane = threadIdx.x;
  const float* a = A + (size_t)r * stride;
  float acc = 0.f;
  for (int c = lane; c < ncols; c += 64) acc += a[c]*w[c];
  acc = wred_sum(acc);
  if (lane == 0) out[r] = acc + (bias ? bias[0] : 0.f);
}

// softmax over l of (e[b,s] + f[b,l]) masked by l < lens[b]; rows = b*80+s
__global__ __launch_bounds__(256) void attsmax_kernel(const float* __restrict__ e,
    const float* __restrict__ f, const int* __restrict__ lens, float* __restrict__ w)
{
  __shared__ float sm[4];
  int bx = blockIdx.x;
  int b = bx / 80;
  int tid = threadIdx.x;
  int len = lens[b];
  bool ok = (tid < 200) && (tid < len);
  float val = ok ? (e[bx] + f[b*200 + tid]) : -1e30f;
  float m = bred_max(val, sm);
  float ex = ok ? __expf(val - m) : 0.f;
  float s = bred_sum(ex, sm);
  if (tid < 200) w[(size_t)bx*200 + tid] = ex / s;
}

// out[b, s, :] = sum_l w[b,s,l] * feats[b,l,:]  written into finalA at coloff
__global__ __launch_bounds__(256) void attapply_kernel(const float* __restrict__ w,
    const float* __restrict__ feats, float* __restrict__ finalA, int coloff)
{
  __shared__ float lw[8][200];
  int b = blockIdx.x, sg = blockIdx.y;
  int tid = threadIdx.x;
  for (int i = tid; i < 1600; i += 256){
    int ss = i / 200, l = i - ss*200;
    lw[ss][l] = w[(size_t)(b*80 + sg*8 + ss)*200 + l];
  }
  __syncthreads();
  float4 acc[8];
#pragma unroll
  for (int s=0;s<8;s++) acc[s] = make_float4(0,0,0,0);
  const float* fb = feats + (size_t)b*200*1024 + tid*4;
  for (int l=0;l<200;l++){
    float4 v = *(const float4*)(fb + (size_t)l*1024);
#pragma unroll
    for (int s=0;s<8;s++){
      float wv = lw[s][l];
      acc[s].x += wv*v.x; acc[s].y += wv*v.y; acc[s].z += wv*v.z; acc[s].w += wv*v.w;
    }
  }
#pragma unroll
  for (int s=0;s<8;s++){
    float* o = finalA + (size_t)(b*80 + sg*8 + s)*2560 + coloff + tid*4;
    *(float4*)o = acc[s];
  }
}

// in-place log_softmax over rows of 10000
__global__ __launch_bounds__(256) void logsmax_kernel(float* __restrict__ out)
{
  __shared__ float buf[10000];
  __shared__ float sm[4];
  int row = blockIdx.x, tid = threadIdx.x;
  float* o = out + (size_t)row * 10000;
  float m = -1e30f;
  for (int i = tid; i < 10000; i += 256){ float v = o[i]; buf[i] = v; m = fmaxf(m, v); }
  m = bred_max(m, sm);
  float s = 0.f;
  for (int i = tid; i < 10000; i += 256) s += __expf(buf[i] - m);
  s = bred_sum(s, sm);
  float lse = m + __logf(s);
  for (int i = tid; i < 10000; i += 256) o[i] = buf[i] - lse;
}

// ---------------------------------------------------------------------------
extern "C" void kernel_launch(void* const* d_in, const int* in_sizes, int n_in,
                              void* d_out, int out_size, void* d_ws, size_t ws_size,
                              hipStream_t stream)
{
  const float* mfeat = (const float*)d_in[0];
  const float* tfeat = (const float*)d_in[1];
  const float* attm  = (const float*)d_in[2];
  const float* attt  = (const float*)d_in[3];
  const float* emb   = (const float*)d_in[4];
  const int* lens_m  = (const int*)d_in[5];
  const int* lens_t  = (const int*)d_in[6];
  const float* Wm  = (const float*)d_in[8];
  const float* bm  = (const float*)d_in[9];
  const float* Wt  = (const float*)d_in[10];
  const float* bt  = (const float*)d_in[11];
  const float* Wmm = (const float*)d_in[12];
  const float* bmm = (const float*)d_in[13];
  const float* Wli = (const float*)d_in[14];
  const float* bli = (const float*)d_in[15];
  const float* Wih = (const float*)d_in[16];
  const float* Whh = (const float*)d_in[17];
  const float* bih = (const float*)d_in[18];
  const float* bhh = (const float*)d_in[19];
  const float* Wsm = (const float*)d_in[20];
  const float* bsm = (const float*)d_in[21];
  const float* Wst = (const float*)d_in[22];
  const float* bst = (const float*)d_in[23];
  const float* Wo  = (const float*)d_in[24];
  const float* bo  = (const float*)d_in[25];
  float* out = (float*)d_out;

  char* ws = (char*)d_ws;
  size_t off = 0;
  auto alloc = [&](size_t bytes)->void* {
    void* p = (void*)(ws + off);
    off += (bytes + 255) & ~(size_t)255;
    return p;
  };
  // f32 scratch
  float* finalA = (float*)alloc(1280UL*2560*4);
  float* moutp  = (float*)alloc(1280UL*1024*4);
  float* toutp  = (float*)alloc(1280UL*1024*4);
  float* mm_out = (float*)alloc(1280UL*512*4);
  float* meanf  = (float*)alloc(128UL*204*4);
  float* m0     = (float*)alloc(128UL*512*4);
  float* X1     = (float*)alloc(128UL*2048*4);
  float* X2     = (float*)alloc(1280UL*2048*4);
  float* e_m = (float*)alloc(1280UL*4); float* e_t = (float*)alloc(1280UL*4);
  float* f_m = (float*)alloc(3200UL*4); float* f_t = (float*)alloc(3200UL*4);
  float* w_m = (float*)alloc(1280UL*200*4); float* w_t = (float*)alloc(1280UL*200*4);
  int* bar = (int*)alloc(256);
  // bf16 scratch
  unsigned short* hbuf0     = (unsigned short*)alloc(16UL*512*2);
  unsigned short* hbuf1     = (unsigned short*)alloc(16UL*512*2);
  unsigned short* attm_bf   = (unsigned short*)alloc(1280UL*1024*2);
  unsigned short* attt_bf   = (unsigned short*)alloc(1280UL*1024*2);
  unsigned short* Wm_bf     = (unsigned short*)alloc(1024UL*1024*2);
  unsigned short* Wt_bf     = (unsigned short*)alloc(1024UL*1024*2);
  unsigned short* Wmm_bf    = (unsigned short*)alloc(512UL*2560*2);
  unsigned short* Wih_bf    = (unsigned short*)alloc(2048UL*512*2);
  unsigned short* Wo_bf     = (unsigned short*)alloc(10000UL*2560*2);
  unsigned short* mm_inp_bf = (unsigned short*)alloc(1280UL*2560*2);
  unsigned short* mm_out_bf = (unsigned short*)alloc(1280UL*512*2);
  unsigned short* m0_bf     = (unsigned short*)alloc(128UL*512*2);
  unsigned short* finalA_bf = (unsigned short*)alloc(1280UL*2560*2);

  auto cvt = [&](const float* s, unsigned short* d, size_t n){
    int n8 = (int)(n/8);
    cvt_bf16_kernel<<<(n8 + 255)/256, 256, 0, stream>>>(s, d, n8);
  };
  // weight + input conversions
  cvt(attm, attm_bf, 1280UL*1024);
  cvt(attt, attt_bf, 1280UL*1024);
  cvt(Wm,  Wm_bf,  1024UL*1024);
  cvt(Wt,  Wt_bf,  1024UL*1024);
  cvt(Wmm, Wmm_bf, 512UL*2560);
  cvt(Wih, Wih_bf, 2048UL*512);
  cvt(Wo,  Wo_bf,  10000UL*2560);
  zero_kernel<<<1, 64, 0, stream>>>(bar, 64);

  // temp_mout / temp_tout pre-activations
  gemm_bb_kernel<<<dim3(10, 8), 256, 0, stream>>>(attm_bf, Wm_bf, bm, nullptr, moutp, 1024, 1024);
  gemm_bb_kernel<<<dim3(10, 8), 256, 0, stream>>>(attt_bf, Wt_bf, bt, nullptr, toutp, 1024, 1024);
  // x * softmax(x) -> bf16 straight into mm_inp columns; emb -> cols [0,512)
  rowsmx_kernel<<<1280, 256, 0, stream>>>(moutp, mm_inp_bf, 2560, 1536);
  rowsmx_kernel<<<1280, 256, 0, stream>>>(toutp, mm_inp_bf, 2560, 512);
  embcopy_kernel<<<(1280*64 + 255)/256, 256, 0, stream>>>(emb, mm_inp_bf);
  // mm_out = mm_inp @ Wmm^T + bmm
  gemm_bb_kernel<<<dim3(10, 4), 256, 0, stream>>>(mm_inp_bf, Wmm_bf, bmm, nullptr, mm_out, 512, 2560);
  cvt(mm_out, mm_out_bf, 1280UL*512);
  // avgpool + m0
  avgpool_kernel<<<128, 256, 0, stream>>>(attt, attm, meanf);
  m0_kernel<<<128, 256, 0, stream>>>(meanf, Wli, bli, m0);
  cvt(m0, m0_bf, 128UL*512);
  // gate preactivations (x-part) for both LSTMs
  gemm_bb_kernel<<<dim3(1, 16), 256, 0, stream>>>(m0_bf, Wih_bf, bih, bhh, X1, 2048, 512);
  gemm_bb_kernel<<<dim3(10, 16), 256, 0, stream>>>(mm_out_bf, Wih_bf, bih, bhh, X2, 2048, 512);
  // fused persistent LSTM (8 + 80 steps)
  lstm_fused_kernel<<<LSTM_NBLK, 256, 0, stream>>>(X1, X2, Whh, hbuf0, hbuf1, finalA, bar);
  // attention score pieces
  proj_kernel<<<1280, 64, 0, stream>>>(finalA, 2560, 512, Wsm, bsm, e_m);
  proj_kernel<<<3200, 64, 0, stream>>>(mfeat, 1024, 1024, Wsm + 512, nullptr, f_m);
  proj_kernel<<<1280, 64, 0, stream>>>(finalA, 2560, 512, Wst, bst, e_t);
  proj_kernel<<<3200, 64, 0, stream>>>(tfeat, 1024, 1024, Wst + 512, nullptr, f_t);
  attsmax_kernel<<<1280, 256, 0, stream>>>(e_t, f_t, lens_t, w_t);
  attsmax_kernel<<<1280, 256, 0, stream>>>(e_m, f_m, lens_m, w_m);
  // weighted sums into finalA cols: att_t2 -> [512,1536), att_m2 -> [1536,2560)
  attapply_kernel<<<dim3(16,10), 256, 0, stream>>>(w_t, tfeat, finalA, 512);
  attapply_kernel<<<dim3(16,10), 256, 0, stream>>>(w_m, mfeat, finalA, 1536);
  // final = finalA @ Wo^T + bo, then in-place log_softmax
  cvt(finalA, finalA_bf, 1280UL*2560);
  gemm_bb_kernel<<<dim3(10, 79), 256, 0, stream>>>(finalA_bf, Wo_bf, bo, nullptr, out, 10000, 2560);
  logsmax_kernel<<<1280, 256, 0, stream>>>(out);
}

// Round 4
// 1047.237 us; speedup vs baseline: 2.9502x; 1.2459x over previous
//
#include <hip/hip_runtime.h>
#include <hip/hip_bf16.h>
#include <math.h>

// Dims: E=512 M=1024 T=1024 H=512 V=10000 ; B=16 S=80 L=200 ; K=10

typedef __bf16 bf16x8 __attribute__((ext_vector_type(8)));
typedef float f32x4 __attribute__((ext_vector_type(4)));
typedef unsigned short u16x8 __attribute__((ext_vector_type(8)));

__device__ inline unsigned short f2b(float f){
  union { float f; unsigned u; } v; v.f = f;
  unsigned u = v.u;
  u += 0x7fff + ((u >> 16) & 1);       // round-to-nearest-even
  return (unsigned short)(u >> 16);
}
__device__ inline float sigm(float x){ return 1.f/(1.f + __expf(-x)); }
__device__ inline float wred_max(float v){ for (int o=32;o;o>>=1) v = fmaxf(v, __shfl_xor(v,o)); return v; }
__device__ inline float wred_sum(float v){ for (int o=32;o;o>>=1) v += __shfl_xor(v,o); return v; }

__device__ inline float bred_max(float v, float* sm){
  v = wred_max(v);
  int w = threadIdx.x >> 6;
  if ((threadIdx.x & 63) == 0) sm[w] = v;
  __syncthreads();
  v = fmaxf(fmaxf(sm[0], sm[1]), fmaxf(sm[2], sm[3]));
  __syncthreads();
  return v;
}
__device__ inline float bred_sum(float v, float* sm){
  v = wred_sum(v);
  int w = threadIdx.x >> 6;
  if ((threadIdx.x & 63) == 0) sm[w] = v;
  __syncthreads();
  v = sm[0] + sm[1] + sm[2] + sm[3];
  __syncthreads();
  return v;
}

#define GLOAD_LDS16(g, l) __builtin_amdgcn_global_load_lds( \
    (const __attribute__((address_space(1))) void*)(g), \
    (__attribute__((address_space(3))) void*)(l), 16, 0, 0)

// ---------------------------------------------------------------------------
// f32 -> bf16 conversion, 8 elems/thread
// ---------------------------------------------------------------------------
__global__ void cvt_bf16_kernel(const float* __restrict__ s, unsigned short* __restrict__ d, int n8){
  int i = blockIdx.x*256 + threadIdx.x;
  if (i >= n8) return;
  float4 a = ((const float4*)s)[i*2];
  float4 b = ((const float4*)s)[i*2+1];
  u16x8 o;
  o[0]=f2b(a.x); o[1]=f2b(a.y); o[2]=f2b(a.z); o[3]=f2b(a.w);
  o[4]=f2b(b.x); o[5]=f2b(b.y); o[6]=f2b(b.z); o[7]=f2b(b.w);
  ((u16x8*)d)[i] = o;
}

__global__ void zero_kernel(int* p, int n){
  int i = blockIdx.x*64 + threadIdx.x;
  if (i < n) p[i] = 0;
}

// ---------------------------------------------------------------------------
// C = A @ B^T + b1 + b2.  A:(R,K) bf16 row-major, B:(N,K) bf16 row-major,
// C:(R,N) f32.  128x128 tile, BK=32, 256 thr (4 waves, 2x2 of 64x64).
// grid = (R/128, ceil(N/128)); R%128==0, K%32==0. global_load_lds staging.
// ---------------------------------------------------------------------------
__global__ __launch_bounds__(256) void gemm_bb_kernel(
    const unsigned short* __restrict__ A, const unsigned short* __restrict__ B,
    const float* __restrict__ bias1, const float* __restrict__ bias2,
    float* __restrict__ C, int N, int K)
{
  __shared__ unsigned short lA[128*32];
  __shared__ unsigned short lB[128*32];
  int tid = threadIdx.x;
  int r0 = blockIdx.x << 7, n0 = blockIdx.y << 7;
  int w = tid >> 6, lane = tid & 63;
  int wr = (w >> 1) << 6, wc = (w & 1) << 6;
  int lm = lane & 15, lq = lane >> 4;
  f32x4 acc[4][4] = {};

  int row0 = tid >> 2, row1 = (tid + 256) >> 2, cc = (tid & 3) << 3;
  const unsigned short* Ag0 = A + (size_t)(r0 + row0)*K + cc;
  const unsigned short* Ag1 = A + (size_t)(r0 + row1)*K + cc;
  int br0 = n0 + row0; if (br0 >= N) br0 = N - 1;
  int br1 = n0 + row1; if (br1 >= N) br1 = N - 1;
  const unsigned short* Bg0 = B + (size_t)br0*K + cc;
  const unsigned short* Bg1 = B + (size_t)br1*K + cc;
  unsigned lb0 = (unsigned)(tid & ~63) * 8;   // u16 index, wave-uniform
  unsigned lb1 = 2048 + lb0;

  for (int k0 = 0; k0 < K; k0 += 32){
    GLOAD_LDS16(Ag0 + k0, &lA[lb0]);
    GLOAD_LDS16(Ag1 + k0, &lA[lb1]);
    GLOAD_LDS16(Bg0 + k0, &lB[lb0]);
    GLOAD_LDS16(Bg1 + k0, &lB[lb1]);
    __syncthreads();
    bf16x8 af[4], bfr[4];
#pragma unroll
    for (int i=0;i<4;i++){
      af[i]  = *(const bf16x8*)&lA[(wr + i*16 + lm)*32 + lq*8];
      bfr[i] = *(const bf16x8*)&lB[(wc + i*16 + lm)*32 + lq*8];
    }
#pragma unroll
    for (int i=0;i<4;i++)
#pragma unroll
      for (int j=0;j<4;j++)
        acc[i][j] = __builtin_amdgcn_mfma_f32_16x16x32_bf16(af[i], bfr[j], acc[i][j], 0, 0, 0);
    __syncthreads();
  }
#pragma unroll
  for (int i=0;i<4;i++){
    int rbase = r0 + wr + i*16 + lq*4;
#pragma unroll
    for (int j=0;j<4;j++){
      int n = n0 + wc + j*16 + lm;
      if (n < N){
        float bv = (bias1 ? bias1[n] : 0.f) + (bias2 ? bias2[n] : 0.f);
#pragma unroll
        for (int rr=0;rr<4;rr++)
          C[(size_t)(rbase + rr)*N + n] = acc[i][j][rr] + bv;
      }
    }
  }
}

// ---------------------------------------------------------------------------
// y = x * softmax(x) over rows of 1024; writes bf16 into out[row*ostride+ooff+i]
// ---------------------------------------------------------------------------
__global__ __launch_bounds__(256) void rowsmx_kernel(const float* __restrict__ X,
    unsigned short* __restrict__ out, int ostride, int ooff)
{
  __shared__ float sm[4];
  int row = blockIdx.x, tid = threadIdx.x;
  const float* xr = X + (size_t)row * 1024;
  float x[4];
#pragma unroll
  for (int j=0;j<4;j++) x[j] = xr[j*256 + tid];
  float m = fmaxf(fmaxf(x[0],x[1]), fmaxf(x[2],x[3]));
  m = bred_max(m, sm);
  float s = 0.f;
#pragma unroll
  for (int j=0;j<4;j++) s += __expf(x[j]-m);
  s = bred_sum(s, sm);
  float inv = 1.f / s;
  unsigned short* o = out + (size_t)row*ostride + ooff;
#pragma unroll
  for (int j=0;j<4;j++) o[j*256 + tid] = f2b(x[j] * (__expf(x[j]-m) * inv));
}

// emb f32 (1280x512) -> bf16 into mm_inp_bf cols [0,512)
__global__ void embcopy_kernel(const float* __restrict__ emb, unsigned short* __restrict__ mmbf){
  int idx = blockIdx.x*256 + threadIdx.x;        // 8-elem chunks
  if (idx >= 1280*64) return;
  int row = idx >> 6, c8 = (idx & 63) << 3;
  const float* s = emb + (size_t)row*512 + c8;
  float4 a = ((const float4*)s)[0], b = ((const float4*)s)[1];
  u16x8 o;
  o[0]=f2b(a.x); o[1]=f2b(a.y); o[2]=f2b(a.z); o[3]=f2b(a.w);
  o[4]=f2b(b.x); o[5]=f2b(b.y); o[6]=f2b(b.z); o[7]=f2b(b.w);
  *(u16x8*)&mmbf[(size_t)row*2560 + c8] = o;
}

// mean_feat (128 rows of 204): cols [0,102)=avgpool(att_tempo), [102,204)=avgpool(att_motion)
__global__ void avgpool_kernel(const float* __restrict__ tempo, const float* __restrict__ motion,
                               float* __restrict__ mf)
{
  int bx = blockIdx.x;          // b*8 + s
  int c = threadIdx.x;
  if (c >= 204) return;
  int b = bx >> 3, s = bx & 7;
  const float* src = (c < 102) ? (tempo  + ((size_t)(b*80 + s*10))*1024 + c*10)
                               : (motion + ((size_t)(b*80 + s*10))*1024 + (c-102)*10);
  float acc = 0.f;
  for (int r=0;r<10;r++){
    const float* p = src + (size_t)r*1024;
#pragma unroll
    for (int cc=0;cc<10;cc++) acc += p[cc];
  }
  mf[bx*204 + c] = acc * 0.01f;
}

// m0 = mean_feat @ Wli^T + bli   (128 x 512, K=204)   fp32
__global__ __launch_bounds__(256) void m0_kernel(const float* __restrict__ mf,
    const float* __restrict__ Wli, const float* __restrict__ bli, float* __restrict__ m0)
{
  __shared__ float rowv[204];
  int bx = blockIdx.x, tid = threadIdx.x;
  if (tid < 204) rowv[tid] = mf[bx*204 + tid];
  __syncthreads();
  for (int c = tid; c < 512; c += 256){
    const float* w = Wli + (size_t)c*204;
    float acc = bli[c];
    for (int k=0;k<204;k++) acc += rowv[k]*w[k];
    m0[bx*512 + c] = acc;
  }
}

// ---------------------------------------------------------------------------
// Persistent fused LSTM: 32 blocks x 256 thr, block j owns units [j*16, j*16+16).
// Whh slice (4 gates x 16 units = 64 rows x 512) cached in LDS as bf16 once.
// Cross-block h exchange via LLC-coherent relaxed atomics (sc0 sc1, bypass
// L1/L2) -- NO cache-flush fences. Ordering: __syncthreads() drains each
// wave's vmcnt before thread 0 bumps the per-step arrival counter bar[sc];
// consumers spin on bar[sc-1]==32 before reading h.  c held in registers
// across all 88 steps (LSTM2 continues from LSTM1 state).
// ---------------------------------------------------------------------------
#define LSTM_NBLK 32
#define HP 520   // padded row stride (u16 elems); 520*2B = 1040B, 8B-aligned

__global__ __launch_bounds__(256) void lstm_fused_kernel(
    const float* __restrict__ X1, const float* __restrict__ X2,
    const float* __restrict__ Whh,
    unsigned long long* __restrict__ hb0, unsigned long long* __restrict__ hb1,
    float* __restrict__ finalA, int* __restrict__ bar)
{
  __shared__ unsigned short w_lds[64*HP];   // 66560 B
  __shared__ unsigned short h_lds[16*HP];   // 16640 B
  __shared__ float gb[4][16][16];           // 4096 B
  __shared__ unsigned short hstage[16][16]; // 512 B [batch][unit]
  int tid = threadIdx.x, j = blockIdx.x;
  int j16 = j*16;
  int lane = tid & 63, w = tid >> 6;
  int lm = lane & 15, lq = lane >> 4;

  // ---- preload Whh slice (rows g*512 + j16 + u), f32 -> bf16, once ----
  for (int i = 0; i < 16; i++){
    int ch = tid + i*256;              // 4096 chunks of 8
    int r = ch >> 6, c8 = (ch & 63) << 3;
    int grow = (r >> 4)*512 + j16 + (r & 15);
    const float* s = Whh + (size_t)grow*512 + c8;
    float4 a = ((const float4*)s)[0], b = ((const float4*)s)[1];
    u16x8 o;
    o[0]=f2b(a.x); o[1]=f2b(a.y); o[2]=f2b(a.z); o[3]=f2b(a.w);
    o[4]=f2b(b.x); o[5]=f2b(b.y); o[6]=f2b(b.z); o[7]=f2b(b.w);
    *(u16x8*)&w_lds[r*HP + c8] = o;
  }

  float c_reg = 0.f;
  int ul = tid & 15, bb = tid >> 4;
  unsigned long long* hbufs[2] = { hb0, hb1 };
  const int wbase = ((w << 4) + lm)*HP;
  const int abase = lm*HP;
  const int koff = lq << 3;
  int sc = 0;

  for (int seg = 0; seg < 2; seg++){
    const float* Xp = seg ? X2 : X1;
    int Tst = seg ? 80 : 8;
    for (int t = 0; t < Tst; t++){
      // ---- wait for previous step's h to be at the LLC ----
      if (sc > 0){
        if (tid == 0){
          while (__hip_atomic_load(&bar[sc-1], __ATOMIC_RELAXED, __HIP_MEMORY_SCOPE_AGENT) < LSTM_NBLK)
            __builtin_amdgcn_s_sleep(1);
        }
        __syncthreads();
      }
      // ---- X gate biases for this step (independent of h; overlaps h load) ----
      size_t xrow = ((size_t)bb*Tst + t)*2048 + j16 + ul;
      float xi = Xp[xrow];
      float xf = Xp[xrow + 512];
      float xg = Xp[xrow + 1024];
      float xo = Xp[xrow + 1536];
      // ---- load h state into LDS (LLC-coherent atomic loads) ----
      if (sc == 0){
        u16x8 z = {0,0,0,0,0,0,0,0};
        for (int i = tid; i < 1024; i += 256){
          int b = i >> 6, c8 = (i & 63) << 3;
          *(u16x8*)&h_lds[b*HP + c8] = z;
        }
      } else {
        const unsigned long long* src = hbufs[sc & 1];
#pragma unroll
        for (int it = 0; it < 4; it++){
          int i = tid + it*256;               // u64 chunk: b = i>>6, c64 = i&63
          int b = i >> 6, c64 = i & 63;
          unsigned long long v = __hip_atomic_load(&src[i], __ATOMIC_RELAXED, __HIP_MEMORY_SCOPE_AGENT);
          *(unsigned long long*)&h_lds[b*HP + (c64 << 2)] = v;
        }
      }
      __syncthreads();
      // ---- gates: wave w computes gate w for 16 units x 16 batches ----
      f32x4 a0 = {0.f,0.f,0.f,0.f}, a1 = {0.f,0.f,0.f,0.f};
#pragma unroll
      for (int k0 = 0; k0 < 512; k0 += 64){
        bf16x8 ha = *(const bf16x8*)&h_lds[abase + k0 + koff];
        bf16x8 wa = *(const bf16x8*)&w_lds[wbase + k0 + koff];
        a0 = __builtin_amdgcn_mfma_f32_16x16x32_bf16(ha, wa, a0, 0, 0, 0);
        bf16x8 hbf = *(const bf16x8*)&h_lds[abase + k0 + 32 + koff];
        bf16x8 wbf = *(const bf16x8*)&w_lds[wbase + k0 + 32 + koff];
        a1 = __builtin_amdgcn_mfma_f32_16x16x32_bf16(hbf, wbf, a1, 0, 0, 0);
      }
      f32x4 acc = a0 + a1;
      *(f32x4*)&gb[w][lm][lq << 2] = acc;   // gb[gate][unit][batch]
      __syncthreads();
      // ---- cell update: thread = (batch bb, unit ul) ----
      float iv = gb[0][ul][bb] + xi;
      float fv = gb[1][ul][bb] + xf;
      float gv = gb[2][ul][bb] + xg;
      float ov = gb[3][ul][bb] + xo;
      c_reg = sigm(fv)*c_reg + sigm(iv)*tanhf(gv);
      float hn = sigm(ov)*tanhf(c_reg);
      hstage[bb][ul] = f2b(hn);
      if (seg) finalA[(size_t)(bb*80 + t)*2560 + j16 + ul] = tanhf(hn);
      __syncthreads();
      // ---- publish h slice to LLC (wave 0: 64 x 8B coherent stores) ----
      if (tid < 64){
        int b = tid >> 2, ch = tid & 3;
        unsigned long long v = *(const unsigned long long*)&hstage[b][ch << 2];
        unsigned long long* dst = hbufs[(sc + 1) & 1] + (size_t)b*64 + (j16 >> 2) + ch;
        __hip_atomic_store(dst, v, __ATOMIC_RELAXED, __HIP_MEMORY_SCOPE_AGENT);
      }
      sc++;
      __syncthreads();   // compiler emits s_waitcnt vmcnt(0) before s_barrier -> stores at LLC
      if (tid == 0)
        __hip_atomic_fetch_add(&bar[sc-1], 1, __ATOMIC_RELAXED, __HIP_MEMORY_SCOPE_AGENT);
    }
  }
}

// out[r] = bias[0] + dot(A[r*stride .. +ncols], w)    one wave per row
__global__ void proj_kernel(const float* __restrict__ A, int stride, int ncols,
                            const float* __restrict__ w, const float* __restrict__ bias,
                            float* __restrict__ out)
{
  int r = blockIdx.x, lane = threadIdx.x;
  const float* a = A + (size_t)r * stride;
  float acc = 0.f;
  for (int c = lane; c < ncols; c += 64) acc += a[c]*w[c];
  acc = wred_sum(acc);
  if (lane == 0) out[r] = acc + (bias ? bias[0] : 0.f);
}

// softmax over l of (e[b,s] + f[b,l]) masked by l < lens[b]; rows = b*80+s
__global__ __launch_bounds__(256) void attsmax_kernel(const float* __restrict__ e,
    const float* __restrict__ f, const int* __restrict__ lens, float* __restrict__ w)
{
  __shared__ float sm[4];
  int bx = blockIdx.x;
  int b = bx / 80;
  int tid = threadIdx.x;
  int len = lens[b];
  bool ok = (tid < 200) && (tid < len);
  float val = ok ? (e[bx] + f[b*200 + tid]) : -1e30f;
  float m = bred_max(val, sm);
  float ex = ok ? __expf(val - m) : 0.f;
  float s = bred_sum(ex, sm);
  if (tid < 200) w[(size_t)bx*200 + tid] = ex / s;
}

// out[b, s, :] = sum_l w[b,s,l] * feats[b,l,:]  written into finalA at coloff
__global__ __launch_bounds__(256) void attapply_kernel(const float* __restrict__ w,
    const float* __restrict__ feats, float* __restrict__ finalA, int coloff)
{
  __shared__ float lw[8][200];
  int b = blockIdx.x, sg = blockIdx.y;
  int tid = threadIdx.x;
  for (int i = tid; i < 1600; i += 256){
    int ss = i / 200, l = i - ss*200;
    lw[ss][l] = w[(size_t)(b*80 + sg*8 + ss)*200 + l];
  }
  __syncthreads();
  float4 acc[8];
#pragma unroll
  for (int s=0;s<8;s++) acc[s] = make_float4(0,0,0,0);
  const float* fb = feats + (size_t)b*200*1024 + tid*4;
  for (int l=0;l<200;l++){
    float4 v = *(const float4*)(fb + (size_t)l*1024);
#pragma unroll
    for (int s=0;s<8;s++){
      float wv = lw[s][l];
      acc[s].x += wv*v.x; acc[s].y += wv*v.y; acc[s].z += wv*v.z; acc[s].w += wv*v.w;
    }
  }
#pragma unroll
  for (int s=0;s<8;s++){
    float* o = finalA + (size_t)(b*80 + sg*8 + s)*2560 + coloff + tid*4;
    *(float4*)o = acc[s];
  }
}

// in-place log_softmax over rows of 10000
__global__ __launch_bounds__(256) void logsmax_kernel(float* __restrict__ out)
{
  __shared__ float buf[10000];
  __shared__ float sm[4];
  int row = blockIdx.x, tid = threadIdx.x;
  float* o = out + (size_t)row * 10000;
  float m = -1e30f;
  for (int i = tid; i < 10000; i += 256){ float v = o[i]; buf[i] = v; m = fmaxf(m, v); }
  m = bred_max(m, sm);
  float s = 0.f;
  for (int i = tid; i < 10000; i += 256) s += __expf(buf[i] - m);
  s = bred_sum(s, sm);
  float lse = m + __logf(s);
  for (int i = tid; i < 10000; i += 256) o[i] = buf[i] - lse;
}

// ---------------------------------------------------------------------------
extern "C" void kernel_launch(void* const* d_in, const int* in_sizes, int n_in,
                              void* d_out, int out_size, void* d_ws, size_t ws_size,
                              hipStream_t stream)
{
  const float* mfeat = (const float*)d_in[0];
  const float* tfeat = (const float*)d_in[1];
  const float* attm  = (const float*)d_in[2];
  const float* attt  = (const float*)d_in[3];
  const float* emb   = (const float*)d_in[4];
  const int* lens_m  = (const int*)d_in[5];
  const int* lens_t  = (const int*)d_in[6];
  const float* Wm  = (const float*)d_in[8];
  const float* bm  = (const float*)d_in[9];
  const float* Wt  = (const float*)d_in[10];
  const float* bt  = (const float*)d_in[11];
  const float* Wmm = (const float*)d_in[12];
  const float* bmm = (const float*)d_in[13];
  const float* Wli = (const float*)d_in[14];
  const float* bli = (const float*)d_in[15];
  const float* Wih = (const float*)d_in[16];
  const float* Whh = (const float*)d_in[17];
  const float* bih = (const float*)d_in[18];
  const float* bhh = (const float*)d_in[19];
  const float* Wsm = (const float*)d_in[20];
  const float* bsm = (const float*)d_in[21];
  const float* Wst = (const float*)d_in[22];
  const float* bst = (const float*)d_in[23];
  const float* Wo  = (const float*)d_in[24];
  const float* bo  = (const float*)d_in[25];
  float* out = (float*)d_out;

  char* ws = (char*)d_ws;
  size_t off = 0;
  auto alloc = [&](size_t bytes)->void* {
    void* p = (void*)(ws + off);
    off += (bytes + 255) & ~(size_t)255;
    return p;
  };
  // f32 scratch
  float* finalA = (float*)alloc(1280UL*2560*4);
  float* moutp  = (float*)alloc(1280UL*1024*4);
  float* toutp  = (float*)alloc(1280UL*1024*4);
  float* mm_out = (float*)alloc(1280UL*512*4);
  float* meanf  = (float*)alloc(128UL*204*4);
  float* m0     = (float*)alloc(128UL*512*4);
  float* X1     = (float*)alloc(128UL*2048*4);
  float* X2     = (float*)alloc(1280UL*2048*4);
  float* e_m = (float*)alloc(1280UL*4); float* e_t = (float*)alloc(1280UL*4);
  float* f_m = (float*)alloc(3200UL*4); float* f_t = (float*)alloc(3200UL*4);
  float* w_m = (float*)alloc(1280UL*200*4); float* w_t = (float*)alloc(1280UL*200*4);
  int* bar = (int*)alloc(128*4);
  // bf16 / u64 scratch
  unsigned long long* hbuf0 = (unsigned long long*)alloc(16UL*512*2);
  unsigned long long* hbuf1 = (unsigned long long*)alloc(16UL*512*2);
  unsigned short* attm_bf   = (unsigned short*)alloc(1280UL*1024*2);
  unsigned short* attt_bf   = (unsigned short*)alloc(1280UL*1024*2);
  unsigned short* Wm_bf     = (unsigned short*)alloc(1024UL*1024*2);
  unsigned short* Wt_bf     = (unsigned short*)alloc(1024UL*1024*2);
  unsigned short* Wmm_bf    = (unsigned short*)alloc(512UL*2560*2);
  unsigned short* Wih_bf    = (unsigned short*)alloc(2048UL*512*2);
  unsigned short* Wo_bf     = (unsigned short*)alloc(10000UL*2560*2);
  unsigned short* mm_inp_bf = (unsigned short*)alloc(1280UL*2560*2);
  unsigned short* mm_out_bf = (unsigned short*)alloc(1280UL*512*2);
  unsigned short* m0_bf     = (unsigned short*)alloc(128UL*512*2);
  unsigned short* finalA_bf = (unsigned short*)alloc(1280UL*2560*2);

  auto cvt = [&](const float* s, unsigned short* d, size_t n){
    int n8 = (int)(n/8);
    cvt_bf16_kernel<<<(n8 + 255)/256, 256, 0, stream>>>(s, d, n8);
  };
  // weight + input conversions
  cvt(attm, attm_bf, 1280UL*1024);
  cvt(attt, attt_bf, 1280UL*1024);
  cvt(Wm,  Wm_bf,  1024UL*1024);
  cvt(Wt,  Wt_bf,  1024UL*1024);
  cvt(Wmm, Wmm_bf, 512UL*2560);
  cvt(Wih, Wih_bf, 2048UL*512);
  cvt(Wo,  Wo_bf,  10000UL*2560);
  zero_kernel<<<2, 64, 0, stream>>>(bar, 128);

  // temp_mout / temp_tout pre-activations
  gemm_bb_kernel<<<dim3(10, 8), 256, 0, stream>>>(attm_bf, Wm_bf, bm, nullptr, moutp, 1024, 1024);
  gemm_bb_kernel<<<dim3(10, 8), 256, 0, stream>>>(attt_bf, Wt_bf, bt, nullptr, toutp, 1024, 1024);
  // x * softmax(x) -> bf16 straight into mm_inp columns; emb -> cols [0,512)
  rowsmx_kernel<<<1280, 256, 0, stream>>>(moutp, mm_inp_bf, 2560, 1536);
  rowsmx_kernel<<<1280, 256, 0, stream>>>(toutp, mm_inp_bf, 2560, 512);
  embcopy_kernel<<<(1280*64 + 255)/256, 256, 0, stream>>>(emb, mm_inp_bf);
  // mm_out = mm_inp @ Wmm^T + bmm
  gemm_bb_kernel<<<dim3(10, 4), 256, 0, stream>>>(mm_inp_bf, Wmm_bf, bmm, nullptr, mm_out, 512, 2560);
  cvt(mm_out, mm_out_bf, 1280UL*512);
  // avgpool + m0
  avgpool_kernel<<<128, 256, 0, stream>>>(attt, attm, meanf);
  m0_kernel<<<128, 256, 0, stream>>>(meanf, Wli, bli, m0);
  cvt(m0, m0_bf, 128UL*512);
  // gate preactivations (x-part) for both LSTMs
  gemm_bb_kernel<<<dim3(1, 16), 256, 0, stream>>>(m0_bf, Wih_bf, bih, bhh, X1, 2048, 512);
  gemm_bb_kernel<<<dim3(10, 16), 256, 0, stream>>>(mm_out_bf, Wih_bf, bih, bhh, X2, 2048, 512);
  // fused persistent LSTM (8 + 80 steps)
  lstm_fused_kernel<<<LSTM_NBLK, 256, 0, stream>>>(X1, X2, Whh, hbuf0, hbuf1, finalA, bar);
  // attention score pieces
  proj_kernel<<<1280, 64, 0, stream>>>(finalA, 2560, 512, Wsm, bsm, e_m);
  proj_kernel<<<3200, 64, 0, stream>>>(mfeat, 1024, 1024, Wsm + 512, nullptr, f_m);
  proj_kernel<<<1280, 64, 0, stream>>>(finalA, 2560, 512, Wst, bst, e_t);
  proj_kernel<<<3200, 64, 0, stream>>>(tfeat, 1024, 1024, Wst + 512, nullptr, f_t);
  attsmax_kernel<<<1280, 256, 0, stream>>>(e_t, f_t, lens_t, w_t);
  attsmax_kernel<<<1280, 256, 0, stream>>>(e_m, f_m, lens_m, w_m);
  // weighted sums into finalA cols: att_t2 -> [512,1536), att_m2 -> [1536,2560)
  attapply_kernel<<<dim3(16,10), 256, 0, stream>>>(w_t, tfeat, finalA, 512);
  attapply_kernel<<<dim3(16,10), 256, 0, stream>>>(w_m, mfeat, finalA, 1536);
  // final = finalA @ Wo^T + bo, then in-place log_softmax
  cvt(finalA, finalA_bf, 1280UL*2560);
  gemm_bb_kernel<<<dim3(10, 79), 256, 0, stream>>>(finalA_bf, Wo_bf, bo, nullptr, out, 10000, 2560);
  logsmax_kernel<<<1280, 256, 0, stream>>>(out);
}